// Round 1
// baseline (391.186 us; speedup 1.0000x reference)
//
#include <hip/hip_runtime.h>
#include <hip/hip_bf16.h>
#include <cstdint>
#include <cstddef>

#define NN 50000
#define NE 800000
#define EPS 1e-5f

// ---------------------------------------------------------------------------
// K1: H[n][s][co] = sum_ci x[n][ci] * W[s][ci][co]    (H: [NN][8][64] fp32)
// grid (782, 8), block 256. 64-node x 64-co tile per s-slice, 4x4 micro-tile.
// ---------------------------------------------------------------------------
__global__ __launch_bounds__(256) void h_gemm(const float* __restrict__ x,
                                              const float* __restrict__ W,
                                              float* __restrict__ H) {
    __shared__ __align__(16) float xs[64 * 64];  // [node_local][ci]
    __shared__ __align__(16) float ws[64 * 64];  // [ci][co]
    const int n0 = blockIdx.x * 64;
    const int s  = blockIdx.y;
    const int t  = threadIdx.x;

    // load x tile (coalesced; rows beyond NN zeroed)
    for (int rep = 0; rep < 16; ++rep) {
        int idx = rep * 256 + t;
        int nl = idx >> 6, ci = idx & 63;
        int n = n0 + nl;
        xs[nl * 64 + ci] = (n < NN) ? x[(size_t)n * 64 + ci] : 0.f;
    }
    // load W slice [64ci][64co]
    const float* Wp = W + s * 4096;
    for (int rep = 0; rep < 16; ++rep) {
        int idx = rep * 256 + t;
        ws[idx] = Wp[idx];
    }
    __syncthreads();

    const int tx = t & 15;   // co group: co = tx*4 + j
    const int ty = t >> 4;   // node group: n = n0 + ty*4 + i
    float acc[4][4] = {{0.f, 0.f, 0.f, 0.f}, {0.f, 0.f, 0.f, 0.f},
                       {0.f, 0.f, 0.f, 0.f}, {0.f, 0.f, 0.f, 0.f}};
    #pragma unroll 8
    for (int ci = 0; ci < 64; ++ci) {
        float a0 = xs[(ty * 4 + 0) * 64 + ci];
        float a1 = xs[(ty * 4 + 1) * 64 + ci];
        float a2 = xs[(ty * 4 + 2) * 64 + ci];
        float a3 = xs[(ty * 4 + 3) * 64 + ci];
        float4 b = *(const float4*)&ws[ci * 64 + tx * 4];
        acc[0][0] += a0 * b.x; acc[0][1] += a0 * b.y; acc[0][2] += a0 * b.z; acc[0][3] += a0 * b.w;
        acc[1][0] += a1 * b.x; acc[1][1] += a1 * b.y; acc[1][2] += a1 * b.z; acc[1][3] += a1 * b.w;
        acc[2][0] += a2 * b.x; acc[2][1] += a2 * b.y; acc[2][2] += a2 * b.z; acc[2][3] += a2 * b.w;
        acc[3][0] += a3 * b.x; acc[3][1] += a3 * b.y; acc[3][2] += a3 * b.z; acc[3][3] += a3 * b.w;
    }
    #pragma unroll
    for (int i = 0; i < 4; ++i) {
        int n = n0 + ty * 4 + i;
        if (n < NN) {
            *(float4*)&H[(size_t)n * 512 + s * 64 + tx * 4] =
                make_float4(acc[i][0], acc[i][1], acc[i][2], acc[i][3]);
        }
    }
}

// ---------------------------------------------------------------------------
// K2: per edge: msg = sum_s B_s * H[src, s, :]; atomicAdd into agg[dst]
// one wave per edge, lane = c_out. grid 200000, block 256 (4 edges/block).
// ---------------------------------------------------------------------------
__global__ __launch_bounds__(256) void edge_kernel(const int* __restrict__ ei,
                                                   const float* __restrict__ attr,
                                                   const float* __restrict__ H,
                                                   float* __restrict__ agg,
                                                   float* __restrict__ cnt) {
    const int e = blockIdx.x * 4 + (threadIdx.x >> 6);
    const int lane = threadIdx.x & 63;
    if (e >= NE) return;
    const int src = ei[e];
    const int dst = ei[NE + e];
    const float f0 = attr[(size_t)e * 3 + 0];
    const float f1 = attr[(size_t)e * 3 + 1];
    const float f2 = attr[(size_t)e * 3 + 2];
    const float g0 = 1.f - f0, g1 = 1.f - f1, g2 = 1.f - f2;
    // s = b0 + 2*b1 + 4*b2, weight = (b0?f0:g0)*(b1?f1:g1)*(b2?f2:g2)
    const float w00 = g1 * g2, w01 = f1 * g2, w10 = g1 * f2, w11 = f1 * f2;
    const float* h = H + (size_t)src * 512 + lane;
    float m = 0.f;
    m += (g0 * w00) * h[0 * 64];
    m += (f0 * w00) * h[1 * 64];
    m += (g0 * w01) * h[2 * 64];
    m += (f0 * w01) * h[3 * 64];
    m += (g0 * w10) * h[4 * 64];
    m += (f0 * w10) * h[5 * 64];
    m += (g0 * w11) * h[6 * 64];
    m += (f0 * w11) * h[7 * 64];
    atomicAdd(&agg[(size_t)dst * 64 + lane], m);
    if (lane == 0) atomicAdd(&cnt[dst], 1.0f);
}

// ---------------------------------------------------------------------------
// K3: out[n] = agg[n]/max(cnt,1) + x[n]@root  (in place in agg buffer = d_out)
//     + per-channel BN partial sums -> atomics into bnsum/bnssq
// grid 782, block 256 (4 waves x 16 nodes each).
// ---------------------------------------------------------------------------
__global__ __launch_bounds__(256) void post_kernel(const float* __restrict__ x,
                                                   const float* __restrict__ root,
                                                   const float* __restrict__ cnt,
                                                   float* __restrict__ outb,
                                                   float* __restrict__ bnsum,
                                                   float* __restrict__ bnssq) {
    __shared__ __align__(16) float rs[64 * 64];  // root [ci][co]
    __shared__ float xrow[4][64];
    __shared__ float red[2][4][64];
    const int t = threadIdx.x, lane = t & 63, w = t >> 6;
    const int n0 = blockIdx.x * 64;
    for (int rep = 0; rep < 16; ++rep) rs[rep * 256 + t] = root[rep * 256 + t];
    __syncthreads();

    float bsum = 0.f, bssq = 0.f;
    for (int i = 0; i < 16; ++i) {
        int n = n0 + w * 16 + i;           // wave-uniform
        if (n < NN) {
            xrow[w][lane] = x[(size_t)n * 64 + lane];
            float rv = 0.f;
            #pragma unroll 16
            for (int ci = 0; ci < 64; ++ci) rv += xrow[w][ci] * rs[ci * 64 + lane];
            float inv = 1.f / fmaxf(cnt[n], 1.f);
            float v = outb[(size_t)n * 64 + lane] * inv + rv;
            outb[(size_t)n * 64 + lane] = v;
            bsum += v;
            bssq += v * v;
        }
    }
    red[0][w][lane] = bsum;
    red[1][w][lane] = bssq;
    __syncthreads();
    if (w == 0) {
        float s = red[0][0][lane] + red[0][1][lane] + red[0][2][lane] + red[0][3][lane];
        float q = red[1][0][lane] + red[1][1][lane] + red[1][2][lane] + red[1][3][lane];
        atomicAdd(&bnsum[lane], s);
        atomicAdd(&bnssq[lane], q);
    }
}

// ---------------------------------------------------------------------------
// K4: BN (training stats) + ELU, in place, float4-vectorized.
// ---------------------------------------------------------------------------
__global__ __launch_bounds__(256) void finalize_kernel(float* __restrict__ outb,
                                                       const float* __restrict__ bnsum,
                                                       const float* __restrict__ bnssq,
                                                       const float* __restrict__ gamma,
                                                       const float* __restrict__ beta) {
    const int idx = blockIdx.x * 256 + threadIdx.x;
    const int total4 = NN * 64 / 4;
    if (idx >= total4) return;
    const int co0 = (idx & 15) * 4;
    float4 v = ((const float4*)outb)[idx];
    float o[4] = {v.x, v.y, v.z, v.w};
    #pragma unroll
    for (int j = 0; j < 4; ++j) {
        int co = co0 + j;
        float mean = bnsum[co] * (1.f / NN);
        float var  = bnssq[co] * (1.f / NN) - mean * mean;
        float sc = rsqrtf(var + EPS) * gamma[co];
        float sh = beta[co] - mean * sc;
        float y = o[j] * sc + sh;
        o[j] = (y > 0.f) ? y : expm1f(y);
    }
    ((float4*)outb)[idx] = make_float4(o[0], o[1], o[2], o[3]);
}

// ---------------------------------------------------------------------------
extern "C" void kernel_launch(void* const* d_in, const int* in_sizes, int n_in,
                              void* d_out, int out_size, void* d_ws, size_t ws_size,
                              hipStream_t stream) {
    const float* x     = (const float*)d_in[0];
    const float* attr  = (const float*)d_in[1];
    const float* W     = (const float*)d_in[2];
    const float* root  = (const float*)d_in[3];
    const float* gamma = (const float*)d_in[4];
    const float* beta  = (const float*)d_in[5];
    const int*   ei    = (const int*)d_in[6];
    float* outb = (float*)d_out;

    char* ws = (char*)d_ws;
    float* H     = (float*)(ws);                  // 102,400,000 B
    float* cnt   = (float*)(ws + 102400000);      //     200,000 B
    float* bnsum = (float*)(ws + 102600000);      //         256 B
    float* bnssq = (float*)(ws + 102600256);      //         256 B

    // zero accumulators (d_out doubles as agg buffer)
    hipMemsetAsync(d_out, 0, (size_t)NN * 64 * sizeof(float), stream);
    hipMemsetAsync(ws + 102400000, 0, 200512, stream);

    h_gemm<<<dim3(782, 8), 256, 0, stream>>>(x, W, H);
    edge_kernel<<<NE / 4, 256, 0, stream>>>(ei, attr, H, outb, cnt);
    post_kernel<<<782, 256, 0, stream>>>(x, root, cnt, outb, bnsum, bnssq);
    finalize_kernel<<<(NN * 64 / 4 + 255) / 256, 256, 0, stream>>>(outb, bnsum, bnssq, gamma, beta);
}

// Round 2
// 386.410 us; speedup vs baseline: 1.0124x; 1.0124x over previous
//
#include <hip/hip_runtime.h>
#include <hip/hip_bf16.h>
#include <cstdint>
#include <cstddef>

#define NN 50000
#define NE 800000
#define EPS 1e-5f

// ---------------- ws layout (bytes) ----------------
// H2    :          0   51,200,000  ushort  H[n][s][co] bf16
// Hroot : 51,200,000   12,800,000  float   (x@root)[n][co]
// EW8   : 64,000,000   25,600,000  float   [e][8] weights (dst-sorted)
// ESRC  : 89,600,000    3,200,000  int     src (dst-sorted)
// OFFS  : 92,800,000      200,004  int     CSR offsets [NN+1]
// CURS  : 93,000,512      200,000  int     scatter cursors
// DEG   : 93,200,512      200,000  int     degree histogram
// PART  : 93,400,512          128  int     scan partials
// PARTX : 93,400,640          128  int     scanned partials
// BNS   : 93,400,768          256  float   BN sum
// BNQ   : 93,401,024          256  float   BN sumsq

static __device__ __forceinline__ ushort f2bf(float f) {
    __hip_bfloat16 h = __float2bfloat16(f);
    return *reinterpret_cast<ushort*>(&h);
}
static __device__ __forceinline__ float bf2f(ushort u) {
    return __uint_as_float(((uint32_t)u) << 16);
}

// ---------------------------------------------------------------------------
// K1: H2[n][s][co] = x[n] @ W[s]  (bf16), slice s==8 -> Hroot = x @ root (f32)
// grid (782, 9), block 256; 64-node x 64-co tile, 4x4 micro-tile.
// ---------------------------------------------------------------------------
__global__ __launch_bounds__(256) void h_gemm(const float* __restrict__ x,
                                              const float* __restrict__ W,
                                              const float* __restrict__ root,
                                              ushort* __restrict__ H2,
                                              float* __restrict__ Hroot) {
    __shared__ __align__(16) float xs[64 * 64];  // [node_local][ci]
    __shared__ __align__(16) float ws[64 * 64];  // [ci][co]
    const int n0 = blockIdx.x * 64;
    const int s  = blockIdx.y;
    const int t  = threadIdx.x;

    for (int rep = 0; rep < 16; ++rep) {
        int idx = rep * 256 + t;
        int nl = idx >> 6, ci = idx & 63;
        int n = n0 + nl;
        xs[idx] = (n < NN) ? x[(size_t)n * 64 + ci] : 0.f;
    }
    const float* Wp = (s < 8) ? (W + s * 4096) : root;
    for (int rep = 0; rep < 16; ++rep) {
        int idx = rep * 256 + t;
        ws[idx] = Wp[idx];
    }
    __syncthreads();

    const int tx = t & 15;   // co = tx*4 + j
    const int ty = t >> 4;   // node = n0 + ty*4 + i
    float acc[4][4] = {{0.f,0.f,0.f,0.f},{0.f,0.f,0.f,0.f},
                       {0.f,0.f,0.f,0.f},{0.f,0.f,0.f,0.f}};
    #pragma unroll 8
    for (int ci = 0; ci < 64; ++ci) {
        float a0 = xs[(ty * 4 + 0) * 64 + ci];
        float a1 = xs[(ty * 4 + 1) * 64 + ci];
        float a2 = xs[(ty * 4 + 2) * 64 + ci];
        float a3 = xs[(ty * 4 + 3) * 64 + ci];
        float4 b = *(const float4*)&ws[ci * 64 + tx * 4];
        acc[0][0] += a0 * b.x; acc[0][1] += a0 * b.y; acc[0][2] += a0 * b.z; acc[0][3] += a0 * b.w;
        acc[1][0] += a1 * b.x; acc[1][1] += a1 * b.y; acc[1][2] += a1 * b.z; acc[1][3] += a1 * b.w;
        acc[2][0] += a2 * b.x; acc[2][1] += a2 * b.y; acc[2][2] += a2 * b.z; acc[2][3] += a2 * b.w;
        acc[3][0] += a3 * b.x; acc[3][1] += a3 * b.y; acc[3][2] += a3 * b.z; acc[3][3] += a3 * b.w;
    }
    #pragma unroll
    for (int i = 0; i < 4; ++i) {
        int n = n0 + ty * 4 + i;
        if (n >= NN) continue;
        if (s < 8) {
            ushort4 h4;
            h4.x = f2bf(acc[i][0]); h4.y = f2bf(acc[i][1]);
            h4.z = f2bf(acc[i][2]); h4.w = f2bf(acc[i][3]);
            *(ushort4*)&H2[(size_t)n * 512 + s * 64 + tx * 4] = h4;
        } else {
            *(float4*)&Hroot[(size_t)n * 64 + tx * 4] =
                make_float4(acc[i][0], acc[i][1], acc[i][2], acc[i][3]);
        }
    }
}

// ---------------------------------------------------------------------------
// K2: degree histogram
// ---------------------------------------------------------------------------
__global__ __launch_bounds__(256) void count_k(const int* __restrict__ ei,
                                               int* __restrict__ deg) {
    int e = blockIdx.x * 256 + threadIdx.x;
    if (e < NE) atomicAdd(&deg[ei[NE + e]], 1);
}

// ---------------------------------------------------------------------------
// K3a/b/c: exclusive scan of deg -> offs (3-kernel block scan, 2048/block)
// ---------------------------------------------------------------------------
__global__ __launch_bounds__(256) void scan1(const int* __restrict__ deg,
                                             int* __restrict__ offs,
                                             int* __restrict__ part) {
    __shared__ int sh[256];
    const int b = blockIdx.x, t = threadIdx.x;
    const int base = b * 2048 + t * 8;
    int v[8]; int sum = 0;
    #pragma unroll
    for (int k = 0; k < 8; ++k) {
        int i = base + k;
        int d = (i < NN) ? deg[i] : 0;
        v[k] = sum; sum += d;
    }
    sh[t] = sum; __syncthreads();
    for (int off = 1; off < 256; off <<= 1) {
        int val = sh[t];
        int add = (t >= off) ? sh[t - off] : 0;
        __syncthreads();
        sh[t] = val + add;
        __syncthreads();
    }
    int excl = (t > 0) ? sh[t - 1] : 0;
    #pragma unroll
    for (int k = 0; k < 8; ++k) {
        int i = base + k;
        if (i < NN) offs[i] = excl + v[k];
    }
    if (t == 255) part[b] = sh[255];
}

__global__ void scan2(const int* __restrict__ part, int* __restrict__ partx,
                      int* __restrict__ offs) {
    if (threadIdx.x == 0 && blockIdx.x == 0) {
        int s = 0;
        for (int i = 0; i < 25; ++i) { partx[i] = s; s += part[i]; }
        offs[NN] = s;   // == NE
    }
}

__global__ __launch_bounds__(256) void scan3(int* __restrict__ offs,
                                             const int* __restrict__ partx,
                                             int* __restrict__ curs) {
    const int b = blockIdx.x, t = threadIdx.x;
    const int add = partx[b];
    #pragma unroll
    for (int k = 0; k < 8; ++k) {
        int i = b * 2048 + t * 8 + k;
        if (i < NN) { int o = offs[i] + add; offs[i] = o; curs[i] = o; }
    }
}

// ---------------------------------------------------------------------------
// K4: scatter edges into dst-sorted arrays (src + 8 precomputed weights)
// ---------------------------------------------------------------------------
__global__ __launch_bounds__(256) void scatter_k(const int* __restrict__ ei,
                                                 const float* __restrict__ attr,
                                                 int* __restrict__ curs,
                                                 int* __restrict__ esrc,
                                                 float* __restrict__ ew8) {
    int e = blockIdx.x * 256 + threadIdx.x;
    if (e >= NE) return;
    const int src = ei[e];
    const int dst = ei[NE + e];
    const float f0 = attr[(size_t)e * 3 + 0];
    const float f1 = attr[(size_t)e * 3 + 1];
    const float f2 = attr[(size_t)e * 3 + 2];
    const float g0 = 1.f - f0, g1 = 1.f - f1, g2 = 1.f - f2;
    const float w00 = g1 * g2, w01 = f1 * g2, w10 = g1 * f2, w11 = f1 * f2;
    int p = atomicAdd(&curs[dst], 1);
    esrc[p] = src;
    *(float4*)&ew8[(size_t)p * 8]     = make_float4(g0 * w00, f0 * w00, g0 * w01, f0 * w01);
    *(float4*)&ew8[(size_t)p * 8 + 4] = make_float4(g0 * w10, f0 * w10, g0 * w11, f0 * w11);
}

// ---------------------------------------------------------------------------
// K5: gather-aggregate. One wave per 16 nodes; lane = co. No atomics on agg.
// out[n] = (sum_j w8 . H2[src_j]) / max(cnt,1) + Hroot[n]; BN partials.
// ---------------------------------------------------------------------------
__global__ __launch_bounds__(256) void aggregate_k(const int* __restrict__ offs,
                                                   const int* __restrict__ esrc,
                                                   const float* __restrict__ ew8,
                                                   const ushort* __restrict__ H2,
                                                   const float* __restrict__ Hroot,
                                                   float* __restrict__ outb,
                                                   float* __restrict__ bnsum,
                                                   float* __restrict__ bnssq) {
    __shared__ float red[2][4][64];
    const int t = threadIdx.x, lane = t & 63, w = t >> 6;
    const int wave_id = blockIdx.x * 4 + w;
    const int nbeg = wave_id * 16;
    float bsum = 0.f, bssq = 0.f;
    for (int n = nbeg; n < nbeg + 16 && n < NN; ++n) {
        const int beg = offs[n], end = offs[n + 1];
        float acc = 0.f;
        for (int j = beg; j < end; ++j) {
            const int src = esrc[j];                       // wave-uniform broadcast
            const float4 wlo = *(const float4*)&ew8[(size_t)j * 8];
            const float4 whi = *(const float4*)&ew8[(size_t)j * 8 + 4];
            const ushort* h = H2 + (size_t)src * 512 + lane;
            acc += wlo.x * bf2f(h[0])   + wlo.y * bf2f(h[64])
                 + wlo.z * bf2f(h[128]) + wlo.w * bf2f(h[192])
                 + whi.x * bf2f(h[256]) + whi.y * bf2f(h[320])
                 + whi.z * bf2f(h[384]) + whi.w * bf2f(h[448]);
        }
        const int cnt = end - beg;
        float v = acc / fmaxf((float)cnt, 1.f) + Hroot[(size_t)n * 64 + lane];
        outb[(size_t)n * 64 + lane] = v;
        bsum += v; bssq += v * v;
    }
    red[0][w][lane] = bsum;
    red[1][w][lane] = bssq;
    __syncthreads();
    if (w == 0) {
        float s = red[0][0][lane] + red[0][1][lane] + red[0][2][lane] + red[0][3][lane];
        float q = red[1][0][lane] + red[1][1][lane] + red[1][2][lane] + red[1][3][lane];
        atomicAdd(&bnsum[lane], s);
        atomicAdd(&bnssq[lane], q);
    }
}

// ---------------------------------------------------------------------------
// K6: BN + ELU, in place, float4.
// ---------------------------------------------------------------------------
__global__ __launch_bounds__(256) void finalize_kernel(float* __restrict__ outb,
                                                       const float* __restrict__ bnsum,
                                                       const float* __restrict__ bnssq,
                                                       const float* __restrict__ gamma,
                                                       const float* __restrict__ beta) {
    const int idx = blockIdx.x * 256 + threadIdx.x;
    const int total4 = NN * 64 / 4;
    if (idx >= total4) return;
    const int co0 = (idx & 15) * 4;
    float4 v = ((const float4*)outb)[idx];
    float o[4] = {v.x, v.y, v.z, v.w};
    #pragma unroll
    for (int j = 0; j < 4; ++j) {
        int co = co0 + j;
        float mean = bnsum[co] * (1.f / NN);
        float var  = bnssq[co] * (1.f / NN) - mean * mean;
        float sc = rsqrtf(var + EPS) * gamma[co];
        float sh = beta[co] - mean * sc;
        float y = o[j] * sc + sh;
        o[j] = (y > 0.f) ? y : expm1f(y);
    }
    ((float4*)outb)[idx] = make_float4(o[0], o[1], o[2], o[3]);
}

// ---------------------------------------------------------------------------
extern "C" void kernel_launch(void* const* d_in, const int* in_sizes, int n_in,
                              void* d_out, int out_size, void* d_ws, size_t ws_size,
                              hipStream_t stream) {
    const float* x     = (const float*)d_in[0];
    const float* attr  = (const float*)d_in[1];
    const float* W     = (const float*)d_in[2];
    const float* root  = (const float*)d_in[3];
    const float* gamma = (const float*)d_in[4];
    const float* beta  = (const float*)d_in[5];
    const int*   ei    = (const int*)d_in[6];
    float* outb = (float*)d_out;

    char* ws = (char*)d_ws;
    ushort* H2    = (ushort*)(ws);
    float*  Hroot = (float*)(ws + 51200000);
    float*  ew8   = (float*)(ws + 64000000);
    int*    esrc  = (int*)(ws + 89600000);
    int*    offs  = (int*)(ws + 92800000);
    int*    curs  = (int*)(ws + 93000512);
    int*    deg   = (int*)(ws + 93200512);
    int*    part  = (int*)(ws + 93400512);
    int*    partx = (int*)(ws + 93400640);
    float*  bnsum = (float*)(ws + 93400768);
    float*  bnssq = (float*)(ws + 93401024);

    // zero deg + part + partx + bnsum + bnssq (contiguous tail region)
    hipMemsetAsync(ws + 93200512, 0, 200768, stream);

    h_gemm<<<dim3(782, 9), 256, 0, stream>>>(x, W, root, H2, Hroot);
    count_k<<<(NE + 255) / 256, 256, 0, stream>>>(ei, deg);
    scan1<<<25, 256, 0, stream>>>(deg, offs, part);
    scan2<<<1, 64, 0, stream>>>(part, partx, offs);
    scan3<<<25, 256, 0, stream>>>(offs, partx, curs);
    scatter_k<<<(NE + 255) / 256, 256, 0, stream>>>(ei, attr, curs, esrc, ew8);
    aggregate_k<<<782, 256, 0, stream>>>(offs, esrc, ew8, H2, Hroot, outb, bnsum, bnssq);
    finalize_kernel<<<(NN * 64 / 4 + 255) / 256, 256, 0, stream>>>(outb, bnsum, bnssq, gamma, beta);
}

// Round 3
// 330.845 us; speedup vs baseline: 1.1824x; 1.1679x over previous
//
#include <hip/hip_runtime.h>
#include <hip/hip_bf16.h>
#include <cstdint>
#include <cstddef>

#define NN 50000
#define NE 800000
#define EPS 1e-5f

// ---------------- ws layout (bytes) ----------------
// H2    :          0   51,200,000  ushort  H[n][s][co] bf16
// Hroot : 51,200,000   12,800,000  float   (x@root)[n][co]
// EW8   : 64,000,000   25,600,000  float   [e][8] weights (dst-sorted)
// ESRC  : 89,600,000    3,200,000  int     src (dst-sorted)
// OFFS  : 92,800,000      200,004  int     CSR offsets [NN+1]
// CURS  : 93,000,512      200,000  int     scatter cursors
// DEG   : 93,200,512      200,000  int     degree histogram
// PART  : 93,400,512          128  int     scan partials
// PARTX : 93,400,640          128  int     scanned partials
// BNS   : 93,400,768          256  float   BN sum
// BNQ   : 93,401,024          256  float   BN sumsq

static __device__ __forceinline__ ushort f2bf(float f) {
    __hip_bfloat16 h = __float2bfloat16(f);
    return *reinterpret_cast<ushort*>(&h);
}
static __device__ __forceinline__ float bf_lo(uint32_t u) {
    return __uint_as_float(u << 16);
}
static __device__ __forceinline__ float bf_hi(uint32_t u) {
    return __uint_as_float(u & 0xffff0000u);
}

// ---------------------------------------------------------------------------
// K1: H2[n][s][co] = x[n] @ W[s]  (bf16), slice s==8 -> Hroot = x @ root (f32)
// grid (782, 9), block 256; 64-node x 64-co tile, 4x4 micro-tile.
// ---------------------------------------------------------------------------
__global__ __launch_bounds__(256) void h_gemm(const float* __restrict__ x,
                                              const float* __restrict__ W,
                                              const float* __restrict__ root,
                                              ushort* __restrict__ H2,
                                              float* __restrict__ Hroot) {
    __shared__ __align__(16) float xs[64 * 64];  // [node_local][ci]
    __shared__ __align__(16) float ws[64 * 64];  // [ci][co]
    const int n0 = blockIdx.x * 64;
    const int s  = blockIdx.y;
    const int t  = threadIdx.x;

    for (int rep = 0; rep < 16; ++rep) {
        int idx = rep * 256 + t;
        int nl = idx >> 6, ci = idx & 63;
        int n = n0 + nl;
        xs[idx] = (n < NN) ? x[(size_t)n * 64 + ci] : 0.f;
    }
    const float* Wp = (s < 8) ? (W + s * 4096) : root;
    for (int rep = 0; rep < 16; ++rep) {
        int idx = rep * 256 + t;
        ws[idx] = Wp[idx];
    }
    __syncthreads();

    const int tx = t & 15;   // co = tx*4 + j
    const int ty = t >> 4;   // node = n0 + ty*4 + i
    float acc[4][4] = {{0.f,0.f,0.f,0.f},{0.f,0.f,0.f,0.f},
                       {0.f,0.f,0.f,0.f},{0.f,0.f,0.f,0.f}};
    #pragma unroll 8
    for (int ci = 0; ci < 64; ++ci) {
        float a0 = xs[(ty * 4 + 0) * 64 + ci];
        float a1 = xs[(ty * 4 + 1) * 64 + ci];
        float a2 = xs[(ty * 4 + 2) * 64 + ci];
        float a3 = xs[(ty * 4 + 3) * 64 + ci];
        float4 b = *(const float4*)&ws[ci * 64 + tx * 4];
        acc[0][0] += a0 * b.x; acc[0][1] += a0 * b.y; acc[0][2] += a0 * b.z; acc[0][3] += a0 * b.w;
        acc[1][0] += a1 * b.x; acc[1][1] += a1 * b.y; acc[1][2] += a1 * b.z; acc[1][3] += a1 * b.w;
        acc[2][0] += a2 * b.x; acc[2][1] += a2 * b.y; acc[2][2] += a2 * b.z; acc[2][3] += a2 * b.w;
        acc[3][0] += a3 * b.x; acc[3][1] += a3 * b.y; acc[3][2] += a3 * b.z; acc[3][3] += a3 * b.w;
    }
    #pragma unroll
    for (int i = 0; i < 4; ++i) {
        int n = n0 + ty * 4 + i;
        if (n >= NN) continue;
        if (s < 8) {
            ushort4 h4;
            h4.x = f2bf(acc[i][0]); h4.y = f2bf(acc[i][1]);
            h4.z = f2bf(acc[i][2]); h4.w = f2bf(acc[i][3]);
            *(ushort4*)&H2[(size_t)n * 512 + s * 64 + tx * 4] = h4;
        } else {
            *(float4*)&Hroot[(size_t)n * 64 + tx * 4] =
                make_float4(acc[i][0], acc[i][1], acc[i][2], acc[i][3]);
        }
    }
}

// ---------------------------------------------------------------------------
// K2: degree histogram
// ---------------------------------------------------------------------------
__global__ __launch_bounds__(256) void count_k(const int* __restrict__ ei,
                                               int* __restrict__ deg) {
    int e = blockIdx.x * 256 + threadIdx.x;
    if (e < NE) atomicAdd(&deg[ei[NE + e]], 1);
}

// ---------------------------------------------------------------------------
// K3a/b/c: exclusive scan of deg -> offs
// ---------------------------------------------------------------------------
__global__ __launch_bounds__(256) void scan1(const int* __restrict__ deg,
                                             int* __restrict__ offs,
                                             int* __restrict__ part) {
    __shared__ int sh[256];
    const int b = blockIdx.x, t = threadIdx.x;
    const int base = b * 2048 + t * 8;
    int v[8]; int sum = 0;
    #pragma unroll
    for (int k = 0; k < 8; ++k) {
        int i = base + k;
        int d = (i < NN) ? deg[i] : 0;
        v[k] = sum; sum += d;
    }
    sh[t] = sum; __syncthreads();
    for (int off = 1; off < 256; off <<= 1) {
        int val = sh[t];
        int add = (t >= off) ? sh[t - off] : 0;
        __syncthreads();
        sh[t] = val + add;
        __syncthreads();
    }
    int excl = (t > 0) ? sh[t - 1] : 0;
    #pragma unroll
    for (int k = 0; k < 8; ++k) {
        int i = base + k;
        if (i < NN) offs[i] = excl + v[k];
    }
    if (t == 255) part[b] = sh[255];
}

__global__ void scan2(const int* __restrict__ part, int* __restrict__ partx,
                      int* __restrict__ offs) {
    if (threadIdx.x == 0 && blockIdx.x == 0) {
        int s = 0;
        for (int i = 0; i < 25; ++i) { partx[i] = s; s += part[i]; }
        offs[NN] = s;   // == NE
    }
}

__global__ __launch_bounds__(256) void scan3(int* __restrict__ offs,
                                             const int* __restrict__ partx,
                                             int* __restrict__ curs) {
    const int b = blockIdx.x, t = threadIdx.x;
    const int add = partx[b];
    #pragma unroll
    for (int k = 0; k < 8; ++k) {
        int i = b * 2048 + t * 8 + k;
        if (i < NN) { int o = offs[i] + add; offs[i] = o; curs[i] = o; }
    }
}

// ---------------------------------------------------------------------------
// K4: scatter edges into dst-sorted arrays (src + 8 precomputed weights)
// ---------------------------------------------------------------------------
__global__ __launch_bounds__(256) void scatter_k(const int* __restrict__ ei,
                                                 const float* __restrict__ attr,
                                                 int* __restrict__ curs,
                                                 int* __restrict__ esrc,
                                                 float* __restrict__ ew8) {
    int e = blockIdx.x * 256 + threadIdx.x;
    if (e >= NE) return;
    const int src = ei[e];
    const int dst = ei[NE + e];
    const float f0 = attr[(size_t)e * 3 + 0];
    const float f1 = attr[(size_t)e * 3 + 1];
    const float f2 = attr[(size_t)e * 3 + 2];
    const float g0 = 1.f - f0, g1 = 1.f - f1, g2 = 1.f - f2;
    const float w00 = g1 * g2, w01 = f1 * g2, w10 = g1 * f2, w11 = f1 * f2;
    int p = atomicAdd(&curs[dst], 1);
    esrc[p] = src;
    *(float4*)&ew8[(size_t)p * 8]     = make_float4(g0 * w00, f0 * w00, g0 * w01, f0 * w01);
    *(float4*)&ew8[(size_t)p * 8 + 4] = make_float4(g0 * w10, f0 * w10, g0 * w11, f0 * w11);
}

// ---------------------------------------------------------------------------
// K5: gather-aggregate. ONE NODE PER WAVE. Lane l covers (s = l>>3,
// co = (l&7)*8 .. +8): one dwordx4 (8 bf16) per edge per lane. Cross-lane
// s-reduction (3 x shfl_xor) once per node. No atomics, no BN here.
// ---------------------------------------------------------------------------
__global__ __launch_bounds__(256) void aggregate_k(const int* __restrict__ offs,
                                                   const int* __restrict__ esrc,
                                                   const float* __restrict__ ew8,
                                                   const ushort* __restrict__ H2,
                                                   const float* __restrict__ Hroot,
                                                   float* __restrict__ outb) {
    const int t = threadIdx.x, lane = t & 63, w = t >> 6;
    const int n = blockIdx.x * 4 + w;
    if (n >= NN) return;
    const int sidx = lane >> 3;          // which s slot this lane owns
    const int cog  = lane & 7;           // co block: co = cog*8 + k
    const int beg = offs[n], end = offs[n + 1];

    float acc[8] = {0.f, 0.f, 0.f, 0.f, 0.f, 0.f, 0.f, 0.f};
    int j = beg;
    for (; j + 1 < end; j += 2) {
        const int a0 = esrc[j];
        const int a1 = esrc[j + 1];
        const float w0 = ew8[(size_t)j * 8 + sidx];
        const float w1 = ew8[(size_t)j * 8 + 8 + sidx];
        const uint4 h0 = *(const uint4*)(H2 + (size_t)a0 * 512 + (lane << 3));
        const uint4 h1 = *(const uint4*)(H2 + (size_t)a1 * 512 + (lane << 3));
        acc[0] += w0 * bf_lo(h0.x); acc[1] += w0 * bf_hi(h0.x);
        acc[2] += w0 * bf_lo(h0.y); acc[3] += w0 * bf_hi(h0.y);
        acc[4] += w0 * bf_lo(h0.z); acc[5] += w0 * bf_hi(h0.z);
        acc[6] += w0 * bf_lo(h0.w); acc[7] += w0 * bf_hi(h0.w);
        acc[0] += w1 * bf_lo(h1.x); acc[1] += w1 * bf_hi(h1.x);
        acc[2] += w1 * bf_lo(h1.y); acc[3] += w1 * bf_hi(h1.y);
        acc[4] += w1 * bf_lo(h1.z); acc[5] += w1 * bf_hi(h1.z);
        acc[6] += w1 * bf_lo(h1.w); acc[7] += w1 * bf_hi(h1.w);
    }
    if (j < end) {
        const int a0 = esrc[j];
        const float w0 = ew8[(size_t)j * 8 + sidx];
        const uint4 h0 = *(const uint4*)(H2 + (size_t)a0 * 512 + (lane << 3));
        acc[0] += w0 * bf_lo(h0.x); acc[1] += w0 * bf_hi(h0.x);
        acc[2] += w0 * bf_lo(h0.y); acc[3] += w0 * bf_hi(h0.y);
        acc[4] += w0 * bf_lo(h0.z); acc[5] += w0 * bf_hi(h0.z);
        acc[6] += w0 * bf_lo(h0.w); acc[7] += w0 * bf_hi(h0.w);
    }
    // reduce over s: lanes {cog, cog+8, ..., cog+56}
    #pragma unroll
    for (int k = 0; k < 8; ++k) {
        float v = acc[k];
        v += __shfl_xor(v, 8, 64);
        v += __shfl_xor(v, 16, 64);
        v += __shfl_xor(v, 32, 64);
        acc[k] = v;
    }
    if (sidx == 0) {
        const float inv = 1.f / fmaxf((float)(end - beg), 1.f);
        const size_t base = (size_t)n * 64 + cog * 8;
        const float4 r0 = *(const float4*)&Hroot[base];
        const float4 r1 = *(const float4*)&Hroot[base + 4];
        *(float4*)&outb[base] = make_float4(acc[0] * inv + r0.x, acc[1] * inv + r0.y,
                                            acc[2] * inv + r0.z, acc[3] * inv + r0.w);
        *(float4*)&outb[base + 4] = make_float4(acc[4] * inv + r1.x, acc[5] * inv + r1.y,
                                                acc[6] * inv + r1.z, acc[7] * inv + r1.w);
    }
}

// ---------------------------------------------------------------------------
// K5b: BN stats over outb. 128 blocks x 256. Thread: fixed co, strided rows.
// ---------------------------------------------------------------------------
__global__ __launch_bounds__(256) void stats_k(const float* __restrict__ outb,
                                               float* __restrict__ bnsum,
                                               float* __restrict__ bnssq) {
    __shared__ float red0[256], red1[256];
    const int t = threadIdx.x;
    const int co = t & 63;
    const int rg = blockIdx.x * 4 + (t >> 6);    // row start, stride 512
    float s = 0.f, q = 0.f;
    for (int r = rg; r < NN; r += 512) {
        float v = outb[(size_t)r * 64 + co];
        s += v; q += v * v;
    }
    red0[t] = s; red1[t] = q;
    __syncthreads();
    if (t < 64) {
        s = red0[t] + red0[t + 64] + red0[t + 128] + red0[t + 192];
        q = red1[t] + red1[t + 64] + red1[t + 128] + red1[t + 192];
        atomicAdd(&bnsum[t], s);
        atomicAdd(&bnssq[t], q);
    }
}

// ---------------------------------------------------------------------------
// K6: BN + ELU, in place, float4.
// ---------------------------------------------------------------------------
__global__ __launch_bounds__(256) void finalize_kernel(float* __restrict__ outb,
                                                       const float* __restrict__ bnsum,
                                                       const float* __restrict__ bnssq,
                                                       const float* __restrict__ gamma,
                                                       const float* __restrict__ beta) {
    const int idx = blockIdx.x * 256 + threadIdx.x;
    const int total4 = NN * 64 / 4;
    if (idx >= total4) return;
    const int co0 = (idx & 15) * 4;
    float4 v = ((const float4*)outb)[idx];
    float o[4] = {v.x, v.y, v.z, v.w};
    #pragma unroll
    for (int j = 0; j < 4; ++j) {
        int co = co0 + j;
        float mean = bnsum[co] * (1.f / NN);
        float var  = bnssq[co] * (1.f / NN) - mean * mean;
        float sc = rsqrtf(var + EPS) * gamma[co];
        float sh = beta[co] - mean * sc;
        float y = o[j] * sc + sh;
        o[j] = (y > 0.f) ? y : expm1f(y);
    }
    ((float4*)outb)[idx] = make_float4(o[0], o[1], o[2], o[3]);
}

// ---------------------------------------------------------------------------
extern "C" void kernel_launch(void* const* d_in, const int* in_sizes, int n_in,
                              void* d_out, int out_size, void* d_ws, size_t ws_size,
                              hipStream_t stream) {
    const float* x     = (const float*)d_in[0];
    const float* attr  = (const float*)d_in[1];
    const float* W     = (const float*)d_in[2];
    const float* root  = (const float*)d_in[3];
    const float* gamma = (const float*)d_in[4];
    const float* beta  = (const float*)d_in[5];
    const int*   ei    = (const int*)d_in[6];
    float* outb = (float*)d_out;

    char* ws = (char*)d_ws;
    ushort* H2    = (ushort*)(ws);
    float*  Hroot = (float*)(ws + 51200000);
    float*  ew8   = (float*)(ws + 64000000);
    int*    esrc  = (int*)(ws + 89600000);
    int*    offs  = (int*)(ws + 92800000);
    int*    curs  = (int*)(ws + 93000512);
    int*    deg   = (int*)(ws + 93200512);
    int*    part  = (int*)(ws + 93400512);
    int*    partx = (int*)(ws + 93400640);
    float*  bnsum = (float*)(ws + 93400768);
    float*  bnssq = (float*)(ws + 93401024);

    // zero deg + part + partx + bnsum + bnssq (contiguous tail region)
    hipMemsetAsync(ws + 93200512, 0, 200768, stream);

    h_gemm<<<dim3(782, 9), 256, 0, stream>>>(x, W, root, H2, Hroot);
    count_k<<<(NE + 255) / 256, 256, 0, stream>>>(ei, deg);
    scan1<<<25, 256, 0, stream>>>(deg, offs, part);
    scan2<<<1, 64, 0, stream>>>(part, partx, offs);
    scan3<<<25, 256, 0, stream>>>(offs, partx, curs);
    scatter_k<<<(NE + 255) / 256, 256, 0, stream>>>(ei, attr, curs, esrc, ew8);
    aggregate_k<<<(NN + 3) / 4, 256, 0, stream>>>(offs, esrc, ew8, H2, Hroot, outb);
    stats_k<<<128, 256, 0, stream>>>(outb, bnsum, bnssq);
    finalize_kernel<<<(NN * 64 / 4 + 255) / 256, 256, 0, stream>>>(outb, bnsum, bnssq, gamma, beta);
}

// Round 4
// 330.137 us; speedup vs baseline: 1.1849x; 1.0021x over previous
//
#include <hip/hip_runtime.h>
#include <hip/hip_bf16.h>
#include <cstdint>
#include <cstddef>

#define NN 50000
#define NE 800000
#define EPS 1e-5f

// ---------------- ws layout (bytes) ----------------
// H2    :          0   51,200,000  ushort  H[n][s][co] bf16
// Hroot : 51,200,000   12,800,000  float   (x@root)[n][co]
// RECS  : 64,000,000    6,400,000  int2    {src, q3} dst-sorted
// OFFS  : 70,400,000      200,064  int     CSR offsets [NN+1]
// CURS  : 70,600,064      200,000  int     scatter cursors
// DEG   : 70,800,064      200,000  int     degree histogram
// PART  : 71,000,064          128  int     scan partials
// PARTX : 71,000,192          128  int     scanned partials
// BNS   : 71,000,320          256  float   BN sum
// BNQ   : 71,000,576          256  float   BN sumsq

static __device__ __forceinline__ ushort f2bf(float f) {
    __hip_bfloat16 h = __float2bfloat16(f);
    return *reinterpret_cast<ushort*>(&h);
}
static __device__ __forceinline__ float bf_lo(uint32_t u) {
    return __uint_as_float(u << 16);
}
static __device__ __forceinline__ float bf_hi(uint32_t u) {
    return __uint_as_float(u & 0xffff0000u);
}

// ---------------------------------------------------------------------------
// K1: H2[n][s][co] = x[n] @ W[s]  (bf16), slice s==8 -> Hroot = x @ root (f32)
// ---------------------------------------------------------------------------
__global__ __launch_bounds__(256) void h_gemm(const float* __restrict__ x,
                                              const float* __restrict__ W,
                                              const float* __restrict__ root,
                                              ushort* __restrict__ H2,
                                              float* __restrict__ Hroot) {
    __shared__ __align__(16) float xs[64 * 64];  // [node_local][ci]
    __shared__ __align__(16) float ws[64 * 64];  // [ci][co]
    const int n0 = blockIdx.x * 64;
    const int s  = blockIdx.y;
    const int t  = threadIdx.x;

    for (int rep = 0; rep < 16; ++rep) {
        int idx = rep * 256 + t;
        int nl = idx >> 6, ci = idx & 63;
        int n = n0 + nl;
        xs[idx] = (n < NN) ? x[(size_t)n * 64 + ci] : 0.f;
    }
    const float* Wp = (s < 8) ? (W + s * 4096) : root;
    for (int rep = 0; rep < 16; ++rep) {
        int idx = rep * 256 + t;
        ws[idx] = Wp[idx];
    }
    __syncthreads();

    const int tx = t & 15;   // co = tx*4 + j
    const int ty = t >> 4;   // node = n0 + ty*4 + i
    float acc[4][4] = {{0.f,0.f,0.f,0.f},{0.f,0.f,0.f,0.f},
                       {0.f,0.f,0.f,0.f},{0.f,0.f,0.f,0.f}};
    #pragma unroll 8
    for (int ci = 0; ci < 64; ++ci) {
        float a0 = xs[(ty * 4 + 0) * 64 + ci];
        float a1 = xs[(ty * 4 + 1) * 64 + ci];
        float a2 = xs[(ty * 4 + 2) * 64 + ci];
        float a3 = xs[(ty * 4 + 3) * 64 + ci];
        float4 b = *(const float4*)&ws[ci * 64 + tx * 4];
        acc[0][0] += a0 * b.x; acc[0][1] += a0 * b.y; acc[0][2] += a0 * b.z; acc[0][3] += a0 * b.w;
        acc[1][0] += a1 * b.x; acc[1][1] += a1 * b.y; acc[1][2] += a1 * b.z; acc[1][3] += a1 * b.w;
        acc[2][0] += a2 * b.x; acc[2][1] += a2 * b.y; acc[2][2] += a2 * b.z; acc[2][3] += a2 * b.w;
        acc[3][0] += a3 * b.x; acc[3][1] += a3 * b.y; acc[3][2] += a3 * b.z; acc[3][3] += a3 * b.w;
    }
    #pragma unroll
    for (int i = 0; i < 4; ++i) {
        int n = n0 + ty * 4 + i;
        if (n >= NN) continue;
        if (s < 8) {
            ushort4 h4;
            h4.x = f2bf(acc[i][0]); h4.y = f2bf(acc[i][1]);
            h4.z = f2bf(acc[i][2]); h4.w = f2bf(acc[i][3]);
            *(ushort4*)&H2[(size_t)n * 512 + s * 64 + tx * 4] = h4;
        } else {
            *(float4*)&Hroot[(size_t)n * 64 + tx * 4] =
                make_float4(acc[i][0], acc[i][1], acc[i][2], acc[i][3]);
        }
    }
}

// ---------------------------------------------------------------------------
// K2: degree histogram
// ---------------------------------------------------------------------------
__global__ __launch_bounds__(256) void count_k(const int* __restrict__ ei,
                                               int* __restrict__ deg) {
    int e = blockIdx.x * 256 + threadIdx.x;
    if (e < NE) atomicAdd(&deg[ei[NE + e]], 1);
}

// ---------------------------------------------------------------------------
// K3a/b/c: exclusive scan of deg -> offs
// ---------------------------------------------------------------------------
__global__ __launch_bounds__(256) void scan1(const int* __restrict__ deg,
                                             int* __restrict__ offs,
                                             int* __restrict__ part) {
    __shared__ int sh[256];
    const int b = blockIdx.x, t = threadIdx.x;
    const int base = b * 2048 + t * 8;
    int v[8]; int sum = 0;
    #pragma unroll
    for (int k = 0; k < 8; ++k) {
        int i = base + k;
        int d = (i < NN) ? deg[i] : 0;
        v[k] = sum; sum += d;
    }
    sh[t] = sum; __syncthreads();
    for (int off = 1; off < 256; off <<= 1) {
        int val = sh[t];
        int add = (t >= off) ? sh[t - off] : 0;
        __syncthreads();
        sh[t] = val + add;
        __syncthreads();
    }
    int excl = (t > 0) ? sh[t - 1] : 0;
    #pragma unroll
    for (int k = 0; k < 8; ++k) {
        int i = base + k;
        if (i < NN) offs[i] = excl + v[k];
    }
    if (t == 255) part[b] = sh[255];
}

__global__ void scan2(const int* __restrict__ part, int* __restrict__ partx,
                      int* __restrict__ offs) {
    if (threadIdx.x == 0 && blockIdx.x == 0) {
        int s = 0;
        for (int i = 0; i < 25; ++i) { partx[i] = s; s += part[i]; }
        offs[NN] = s;   // == NE
    }
}

__global__ __launch_bounds__(256) void scan3(int* __restrict__ offs,
                                             const int* __restrict__ partx,
                                             int* __restrict__ curs) {
    const int b = blockIdx.x, t = threadIdx.x;
    const int add = partx[b];
    #pragma unroll
    for (int k = 0; k < 8; ++k) {
        int i = b * 2048 + t * 8 + k;
        if (i < NN) { int o = offs[i] + add; offs[i] = o; curs[i] = o; }
    }
}

// ---------------------------------------------------------------------------
// K4: scatter edges: record = {src, q3} where q3 = 3x10-bit quantized fracs.
// 8-byte random writes (was 36 B in round 3).
// ---------------------------------------------------------------------------
__global__ __launch_bounds__(256) void scatter_k(const int* __restrict__ ei,
                                                 const float* __restrict__ attr,
                                                 int* __restrict__ curs,
                                                 int2* __restrict__ recs) {
    int e = blockIdx.x * 256 + threadIdx.x;
    if (e >= NE) return;
    const int src = ei[e];
    const int dst = ei[NE + e];
    const float f0 = attr[(size_t)e * 3 + 0];
    const float f1 = attr[(size_t)e * 3 + 1];
    const float f2 = attr[(size_t)e * 3 + 2];
    const uint32_t q = (uint32_t)rintf(f0 * 1023.f)
                     | ((uint32_t)rintf(f1 * 1023.f) << 10)
                     | ((uint32_t)rintf(f2 * 1023.f) << 20);
    int p = atomicAdd(&curs[dst], 1);
    recs[p] = make_int2(src, (int)q);
}

// ---------------------------------------------------------------------------
// K5: gather-aggregate. One node per wave; lane l: s=l>>3, co=(l&7)*8..+8.
// Per edge: 8 B contiguous rec + 16 B H2 dwordx4 per lane. Unroll 4 for MLP.
// ---------------------------------------------------------------------------
__global__ __launch_bounds__(256) void aggregate_k(const int* __restrict__ offs,
                                                   const int2* __restrict__ recs,
                                                   const ushort* __restrict__ H2,
                                                   const float* __restrict__ Hroot,
                                                   float* __restrict__ outb) {
    const int t = threadIdx.x, lane = t & 63, w = t >> 6;
    const int n = blockIdx.x * 4 + w;
    if (n >= NN) return;
    const int sidx = lane >> 3;          // s slot this lane owns
    const int cog  = lane & 7;           // co block
    // per-lane selector constants: t_k = c_k + s_k * f_k  (= f or 1-f)
    const float sg0 = (sidx & 1) ? 1.f : -1.f, cc0 = (sidx & 1) ? 0.f : 1.f;
    const float sg1 = (sidx & 2) ? 1.f : -1.f, cc1 = (sidx & 2) ? 0.f : 1.f;
    const float sg2 = (sidx & 4) ? 1.f : -1.f, cc2 = (sidx & 4) ? 0.f : 1.f;
    const int beg = offs[n], end = offs[n + 1];
    const size_t loff = (size_t)(lane << 3);

    float acc[8] = {0.f, 0.f, 0.f, 0.f, 0.f, 0.f, 0.f, 0.f};

#define DECODE_W(qv, wv)                                                     \
    {                                                                        \
        const uint32_t q_ = (uint32_t)(qv);                                  \
        const float f0_ = (float)(q_ & 1023u) * (1.f / 1023.f);              \
        const float f1_ = (float)((q_ >> 10) & 1023u) * (1.f / 1023.f);      \
        const float f2_ = (float)((q_ >> 20) & 1023u) * (1.f / 1023.f);      \
        wv = (cc0 + sg0 * f0_) * ((cc1 + sg1 * f1_) * (cc2 + sg2 * f2_));    \
    }
#define ACCUM(wv, h)                                                         \
    acc[0] += (wv) * bf_lo((h).x); acc[1] += (wv) * bf_hi((h).x);            \
    acc[2] += (wv) * bf_lo((h).y); acc[3] += (wv) * bf_hi((h).y);            \
    acc[4] += (wv) * bf_lo((h).z); acc[5] += (wv) * bf_hi((h).z);            \
    acc[6] += (wv) * bf_lo((h).w); acc[7] += (wv) * bf_hi((h).w);

    int j = beg;
    for (; j + 3 < end; j += 4) {
        const int2 r0 = recs[j];
        const int2 r1 = recs[j + 1];
        const int2 r2 = recs[j + 2];
        const int2 r3 = recs[j + 3];
        const uint4 h0 = *(const uint4*)(H2 + (size_t)r0.x * 512 + loff);
        const uint4 h1 = *(const uint4*)(H2 + (size_t)r1.x * 512 + loff);
        const uint4 h2 = *(const uint4*)(H2 + (size_t)r2.x * 512 + loff);
        const uint4 h3 = *(const uint4*)(H2 + (size_t)r3.x * 512 + loff);
        float w0, w1, w2, w3;
        DECODE_W(r0.y, w0); DECODE_W(r1.y, w1);
        DECODE_W(r2.y, w2); DECODE_W(r3.y, w3);
        ACCUM(w0, h0); ACCUM(w1, h1); ACCUM(w2, h2); ACCUM(w3, h3);
    }
    for (; j < end; ++j) {
        const int2 r0 = recs[j];
        const uint4 h0 = *(const uint4*)(H2 + (size_t)r0.x * 512 + loff);
        float w0;
        DECODE_W(r0.y, w0);
        ACCUM(w0, h0);
    }
#undef DECODE_W
#undef ACCUM

    // reduce over s: lanes {cog, cog+8, ..., cog+56}
    #pragma unroll
    for (int k = 0; k < 8; ++k) {
        float v = acc[k];
        v += __shfl_xor(v, 8, 64);
        v += __shfl_xor(v, 16, 64);
        v += __shfl_xor(v, 32, 64);
        acc[k] = v;
    }
    if (sidx == 0) {
        const float inv = 1.f / fmaxf((float)(end - beg), 1.f);
        const size_t base = (size_t)n * 64 + cog * 8;
        const float4 r0 = *(const float4*)&Hroot[base];
        const float4 r1 = *(const float4*)&Hroot[base + 4];
        *(float4*)&outb[base] = make_float4(acc[0] * inv + r0.x, acc[1] * inv + r0.y,
                                            acc[2] * inv + r0.z, acc[3] * inv + r0.w);
        *(float4*)&outb[base + 4] = make_float4(acc[4] * inv + r1.x, acc[5] * inv + r1.y,
                                                acc[6] * inv + r1.z, acc[7] * inv + r1.w);
    }
}

// ---------------------------------------------------------------------------
// K5b: BN stats over outb.
// ---------------------------------------------------------------------------
__global__ __launch_bounds__(256) void stats_k(const float* __restrict__ outb,
                                               float* __restrict__ bnsum,
                                               float* __restrict__ bnssq) {
    __shared__ float red0[256], red1[256];
    const int t = threadIdx.x;
    const int co = t & 63;
    const int rg = blockIdx.x * 4 + (t >> 6);
    float s = 0.f, q = 0.f;
    for (int r = rg; r < NN; r += 512) {
        float v = outb[(size_t)r * 64 + co];
        s += v; q += v * v;
    }
    red0[t] = s; red1[t] = q;
    __syncthreads();
    if (t < 64) {
        s = red0[t] + red0[t + 64] + red0[t + 128] + red0[t + 192];
        q = red1[t] + red1[t + 64] + red1[t + 128] + red1[t + 192];
        atomicAdd(&bnsum[t], s);
        atomicAdd(&bnssq[t], q);
    }
}

// ---------------------------------------------------------------------------
// K6: BN + ELU, in place, float4.
// ---------------------------------------------------------------------------
__global__ __launch_bounds__(256) void finalize_kernel(float* __restrict__ outb,
                                                       const float* __restrict__ bnsum,
                                                       const float* __restrict__ bnssq,
                                                       const float* __restrict__ gamma,
                                                       const float* __restrict__ beta) {
    const int idx = blockIdx.x * 256 + threadIdx.x;
    const int total4 = NN * 64 / 4;
    if (idx >= total4) return;
    const int co0 = (idx & 15) * 4;
    float4 v = ((const float4*)outb)[idx];
    float o[4] = {v.x, v.y, v.z, v.w};
    #pragma unroll
    for (int j = 0; j < 4; ++j) {
        int co = co0 + j;
        float mean = bnsum[co] * (1.f / NN);
        float var  = bnssq[co] * (1.f / NN) - mean * mean;
        float sc = rsqrtf(var + EPS) * gamma[co];
        float sh = beta[co] - mean * sc;
        float y = o[j] * sc + sh;
        o[j] = (y > 0.f) ? y : expm1f(y);
    }
    ((float4*)outb)[idx] = make_float4(o[0], o[1], o[2], o[3]);
}

// ---------------------------------------------------------------------------
extern "C" void kernel_launch(void* const* d_in, const int* in_sizes, int n_in,
                              void* d_out, int out_size, void* d_ws, size_t ws_size,
                              hipStream_t stream) {
    const float* x     = (const float*)d_in[0];
    const float* attr  = (const float*)d_in[1];
    const float* W     = (const float*)d_in[2];
    const float* root  = (const float*)d_in[3];
    const float* gamma = (const float*)d_in[4];
    const float* beta  = (const float*)d_in[5];
    const int*   ei    = (const int*)d_in[6];
    float* outb = (float*)d_out;

    char* ws = (char*)d_ws;
    ushort* H2    = (ushort*)(ws);
    float*  Hroot = (float*)(ws + 51200000);
    int2*   recs  = (int2*)(ws + 64000000);
    int*    offs  = (int*)(ws + 70400000);
    int*    curs  = (int*)(ws + 70600064);
    int*    deg   = (int*)(ws + 70800064);
    int*    part  = (int*)(ws + 71000064);
    int*    partx = (int*)(ws + 71000192);
    float*  bnsum = (float*)(ws + 71000320);
    float*  bnssq = (float*)(ws + 71000576);

    // zero deg + part + partx + bnsum + bnssq (contiguous tail region)
    hipMemsetAsync(ws + 70800064, 0, 200768, stream);

    h_gemm<<<dim3(782, 9), 256, 0, stream>>>(x, W, root, H2, Hroot);
    count_k<<<(NE + 255) / 256, 256, 0, stream>>>(ei, deg);
    scan1<<<25, 256, 0, stream>>>(deg, offs, part);
    scan2<<<1, 64, 0, stream>>>(part, partx, offs);
    scan3<<<25, 256, 0, stream>>>(offs, partx, curs);
    scatter_k<<<(NE + 255) / 256, 256, 0, stream>>>(ei, attr, curs, recs);
    aggregate_k<<<(NN + 3) / 4, 256, 0, stream>>>(offs, recs, H2, Hroot, outb);
    stats_k<<<128, 256, 0, stream>>>(outb, bnsum, bnssq);
    finalize_kernel<<<(NN * 64 / 4 + 255) / 256, 256, 0, stream>>>(outb, bnsum, bnssq, gamma, beta);
}

// Round 5
// 292.742 us; speedup vs baseline: 1.3363x; 1.1277x over previous
//
#include <hip/hip_runtime.h>
#include <hip/hip_bf16.h>
#include <cstdint>
#include <cstddef>

#define NN 50000
#define NE 800000
#define EPS 1e-5f

typedef short bf16x8 __attribute__((ext_vector_type(8)));
typedef float f32x4  __attribute__((ext_vector_type(4)));

// ---------------- ws layout (bytes) ----------------
// H2    :          0   51,200,000  ushort  H[n][s][co] bf16
// Hroot : 51,200,000   12,800,000  float   (x@root)[n][co]
// RECS  : 64,000,000    6,400,000  int2    {src, q3} dst-sorted
// OFFS  : 70,400,000      200,064  int     CSR offsets [NN+1]
// CURS  : 70,600,064      200,000  int     scatter cursors
// DEG   : 70,800,064      200,000  int     degree histogram
// PART  : 71,000,064          128  int     scan partials
// PARTX : 71,000,192          128  int     scanned partials
// BNS   : 71,000,320          256  float   BN sum
// BNQ   : 71,000,576          256  float   BN sumsq
// WTG   : 71,000,832      147,456  ushort  WTg[s][co][ci] bf16 (s=8 is root)

static __device__ __forceinline__ ushort f2bf(float f) {
    __hip_bfloat16 h = __float2bfloat16(f);
    return *reinterpret_cast<ushort*>(&h);
}
static __device__ __forceinline__ float bf_lo(uint32_t u) {
    return __uint_as_float(u << 16);
}
static __device__ __forceinline__ float bf_hi(uint32_t u) {
    return __uint_as_float(u & 0xffff0000u);
}
static __device__ __forceinline__ uint32_t pack2(float a, float b) {
    return (uint32_t)f2bf(a) | ((uint32_t)f2bf(b) << 16);
}

// ---------------------------------------------------------------------------
// K0: transpose W (+root as s==8) to bf16 WTg[s][co][ci]. 147 KB, one-time.
// ---------------------------------------------------------------------------
__global__ __launch_bounds__(256) void wt_prep(const float* __restrict__ W,
                                               const float* __restrict__ root,
                                               ushort* __restrict__ WTg) {
    const int idx = blockIdx.x * 256 + threadIdx.x;      // [0, 9*4096)
    if (idx >= 9 * 4096) return;
    const int s  = idx >> 12;
    const int co = (idx >> 6) & 63;
    const int ci = idx & 63;
    const float v = (s < 8) ? W[s * 4096 + ci * 64 + co] : root[ci * 64 + co];
    WTg[idx] = f2bf(v);   // WTg[s][co][ci]
}

// ---------------------------------------------------------------------------
// K1: H2[n][s][co] = x[n] @ W[s] (bf16 out), s==8 -> Hroot (f32 out).
// MFMA 16x16x32 bf16. Block 256 = 4 waves; block tile = 64 nodes x 64 co,
// one s per blockIdx.y. Wave w: nodes w*16..+16, all 64 co (4 co-tiles).
// LDS tiles XOR-swizzled (T2) so all frag reads are conflict-free b128.
// ---------------------------------------------------------------------------
__global__ __launch_bounds__(256) void h_mfma(const float* __restrict__ x,
                                              const ushort* __restrict__ WTg,
                                              ushort* __restrict__ H2,
                                              float* __restrict__ Hroot) {
    __shared__ __align__(16) ushort XA[64 * 64];   // [node][ci] bf16, swizzled
    __shared__ __align__(16) ushort WT[64 * 64];   // [co][ci]  bf16, swizzled
    const int n0 = blockIdx.x * 64;
    const int s  = blockIdx.y;
    const int t  = threadIdx.x;

    // stage XA: 512 virtual threads, each 8 bf16 (one b128 write)
    #pragma unroll
    for (int rep = 0; rep < 2; ++rep) {
        const int vt   = rep * 256 + t;
        const int row  = vt >> 3;          // node local 0..63
        const int col8 = vt & 7;           // 8-elem group
        const int n = n0 + row;
        uint4 u;
        if (n < NN) {
            const float4 v0 = *(const float4*)&x[(size_t)n * 64 + col8 * 8];
            const float4 v1 = *(const float4*)&x[(size_t)n * 64 + col8 * 8 + 4];
            u.x = pack2(v0.x, v0.y); u.y = pack2(v0.z, v0.w);
            u.z = pack2(v1.x, v1.y); u.w = pack2(v1.z, v1.w);
        } else {
            u = make_uint4(0, 0, 0, 0);
        }
        const int idx = (row * 64 + col8 * 8) ^ ((row & 7) << 3);
        *(uint4*)&XA[idx] = u;
    }
    // stage WT: direct bf16 copy from WTg[s]
    const ushort* wsrc = WTg + s * 4096;
    #pragma unroll
    for (int rep = 0; rep < 2; ++rep) {
        const int vt   = rep * 256 + t;
        const int row  = vt >> 3;          // co 0..63
        const int col8 = vt & 7;
        const uint4 u = *(const uint4*)&wsrc[row * 64 + col8 * 8];
        const int idx = (row * 64 + col8 * 8) ^ ((row & 7) << 3);
        *(uint4*)&WT[idx] = u;
    }
    __syncthreads();

    const int w    = t >> 6;
    const int lane = t & 63;
    const int mrow = lane & 15;     // A row / B col within tile
    const int kgrp = lane >> 4;     // k group (8 k each)
    const int swz  = (mrow & 7) << 3;

    // A frags: nodes w*16+mrow, k-tiles 0/1
    bf16x8 a0 = *(const bf16x8*)&XA[(((w * 16 + mrow) * 64) + 0 * 32 + kgrp * 8) ^ swz];
    bf16x8 a1 = *(const bf16x8*)&XA[(((w * 16 + mrow) * 64) + 1 * 32 + kgrp * 8) ^ swz];

    f32x4 acc[4];
    #pragma unroll
    for (int ct = 0; ct < 4; ++ct) {
        acc[ct] = (f32x4){0.f, 0.f, 0.f, 0.f};
        const int brow = ct * 16 + mrow;
        bf16x8 b0 = *(const bf16x8*)&WT[((brow * 64) + 0 * 32 + kgrp * 8) ^ swz];
        bf16x8 b1 = *(const bf16x8*)&WT[((brow * 64) + 1 * 32 + kgrp * 8) ^ swz];
        acc[ct] = __builtin_amdgcn_mfma_f32_16x16x32_bf16(a0, b0, acc[ct], 0, 0, 0);
        acc[ct] = __builtin_amdgcn_mfma_f32_16x16x32_bf16(a1, b1, acc[ct], 0, 0, 0);
    }

    // store: C row = kgrp*4 + r, col = mrow (per m89-verified layout)
    #pragma unroll
    for (int ct = 0; ct < 4; ++ct) {
        const int co = ct * 16 + mrow;
        #pragma unroll
        for (int r = 0; r < 4; ++r) {
            const int n = n0 + w * 16 + kgrp * 4 + r;
            if (n < NN) {
                if (s < 8) H2[(size_t)n * 512 + s * 64 + co] = f2bf(acc[ct][r]);
                else       Hroot[(size_t)n * 64 + co] = acc[ct][r];
            }
        }
    }
}

// ---------------------------------------------------------------------------
// K2: degree histogram
// ---------------------------------------------------------------------------
__global__ __launch_bounds__(256) void count_k(const int* __restrict__ ei,
                                               int* __restrict__ deg) {
    int e = blockIdx.x * 256 + threadIdx.x;
    if (e < NE) atomicAdd(&deg[ei[NE + e]], 1);
}

// ---------------------------------------------------------------------------
// K3a/b/c: exclusive scan of deg -> offs
// ---------------------------------------------------------------------------
__global__ __launch_bounds__(256) void scan1(const int* __restrict__ deg,
                                             int* __restrict__ offs,
                                             int* __restrict__ part) {
    __shared__ int sh[256];
    const int b = blockIdx.x, t = threadIdx.x;
    const int base = b * 2048 + t * 8;
    int v[8]; int sum = 0;
    #pragma unroll
    for (int k = 0; k < 8; ++k) {
        int i = base + k;
        int d = (i < NN) ? deg[i] : 0;
        v[k] = sum; sum += d;
    }
    sh[t] = sum; __syncthreads();
    for (int off = 1; off < 256; off <<= 1) {
        int val = sh[t];
        int add = (t >= off) ? sh[t - off] : 0;
        __syncthreads();
        sh[t] = val + add;
        __syncthreads();
    }
    int excl = (t > 0) ? sh[t - 1] : 0;
    #pragma unroll
    for (int k = 0; k < 8; ++k) {
        int i = base + k;
        if (i < NN) offs[i] = excl + v[k];
    }
    if (t == 255) part[b] = sh[255];
}

__global__ void scan2(const int* __restrict__ part, int* __restrict__ partx,
                      int* __restrict__ offs) {
    if (threadIdx.x == 0 && blockIdx.x == 0) {
        int s = 0;
        for (int i = 0; i < 25; ++i) { partx[i] = s; s += part[i]; }
        offs[NN] = s;   // == NE
    }
}

__global__ __launch_bounds__(256) void scan3(int* __restrict__ offs,
                                             const int* __restrict__ partx,
                                             int* __restrict__ curs) {
    const int b = blockIdx.x, t = threadIdx.x;
    const int add = partx[b];
    #pragma unroll
    for (int k = 0; k < 8; ++k) {
        int i = b * 2048 + t * 8 + k;
        if (i < NN) { int o = offs[i] + add; offs[i] = o; curs[i] = o; }
    }
}

// ---------------------------------------------------------------------------
// K4: scatter edges: record = {src, q3}, q3 = 3x10-bit quantized fracs.
// ---------------------------------------------------------------------------
__global__ __launch_bounds__(256) void scatter_k(const int* __restrict__ ei,
                                                 const float* __restrict__ attr,
                                                 int* __restrict__ curs,
                                                 int2* __restrict__ recs) {
    int e = blockIdx.x * 256 + threadIdx.x;
    if (e >= NE) return;
    const int src = ei[e];
    const int dst = ei[NE + e];
    const float f0 = attr[(size_t)e * 3 + 0];
    const float f1 = attr[(size_t)e * 3 + 1];
    const float f2 = attr[(size_t)e * 3 + 2];
    const uint32_t q = (uint32_t)rintf(f0 * 1023.f)
                     | ((uint32_t)rintf(f1 * 1023.f) << 10)
                     | ((uint32_t)rintf(f2 * 1023.f) << 20);
    int p = atomicAdd(&curs[dst], 1);
    recs[p] = make_int2(src, (int)q);
}

// ---------------------------------------------------------------------------
// K5: gather-aggregate. One node per wave; lane l: s=l>>3, co=(l&7)*8..+8.
// ---------------------------------------------------------------------------
__global__ __launch_bounds__(256) void aggregate_k(const int* __restrict__ offs,
                                                   const int2* __restrict__ recs,
                                                   const ushort* __restrict__ H2,
                                                   const float* __restrict__ Hroot,
                                                   float* __restrict__ outb) {
    const int t = threadIdx.x, lane = t & 63, w = t >> 6;
    const int n = blockIdx.x * 4 + w;
    if (n >= NN) return;
    const int sidx = lane >> 3;
    const int cog  = lane & 7;
    const float sg0 = (sidx & 1) ? 1.f : -1.f, cc0 = (sidx & 1) ? 0.f : 1.f;
    const float sg1 = (sidx & 2) ? 1.f : -1.f, cc1 = (sidx & 2) ? 0.f : 1.f;
    const float sg2 = (sidx & 4) ? 1.f : -1.f, cc2 = (sidx & 4) ? 0.f : 1.f;
    const int beg = offs[n], end = offs[n + 1];
    const size_t loff = (size_t)(lane << 3);

    float acc[8] = {0.f, 0.f, 0.f, 0.f, 0.f, 0.f, 0.f, 0.f};

#define DECODE_W(qv, wv)                                                     \
    {                                                                        \
        const uint32_t q_ = (uint32_t)(qv);                                  \
        const float f0_ = (float)(q_ & 1023u) * (1.f / 1023.f);              \
        const float f1_ = (float)((q_ >> 10) & 1023u) * (1.f / 1023.f);      \
        const float f2_ = (float)((q_ >> 20) & 1023u) * (1.f / 1023.f);      \
        wv = (cc0 + sg0 * f0_) * ((cc1 + sg1 * f1_) * (cc2 + sg2 * f2_));    \
    }
#define ACCUM(wv, h)                                                         \
    acc[0] += (wv) * bf_lo((h).x); acc[1] += (wv) * bf_hi((h).x);            \
    acc[2] += (wv) * bf_lo((h).y); acc[3] += (wv) * bf_hi((h).y);            \
    acc[4] += (wv) * bf_lo((h).z); acc[5] += (wv) * bf_hi((h).z);            \
    acc[6] += (wv) * bf_lo((h).w); acc[7] += (wv) * bf_hi((h).w);

    int j = beg;
    for (; j + 3 < end; j += 4) {
        const int2 r0 = recs[j];
        const int2 r1 = recs[j + 1];
        const int2 r2 = recs[j + 2];
        const int2 r3 = recs[j + 3];
        const uint4 h0 = *(const uint4*)(H2 + (size_t)r0.x * 512 + loff);
        const uint4 h1 = *(const uint4*)(H2 + (size_t)r1.x * 512 + loff);
        const uint4 h2 = *(const uint4*)(H2 + (size_t)r2.x * 512 + loff);
        const uint4 h3 = *(const uint4*)(H2 + (size_t)r3.x * 512 + loff);
        float w0, w1, w2, w3;
        DECODE_W(r0.y, w0); DECODE_W(r1.y, w1);
        DECODE_W(r2.y, w2); DECODE_W(r3.y, w3);
        ACCUM(w0, h0); ACCUM(w1, h1); ACCUM(w2, h2); ACCUM(w3, h3);
    }
    for (; j < end; ++j) {
        const int2 r0 = recs[j];
        const uint4 h0 = *(const uint4*)(H2 + (size_t)r0.x * 512 + loff);
        float w0;
        DECODE_W(r0.y, w0);
        ACCUM(w0, h0);
    }
#undef DECODE_W
#undef ACCUM

    #pragma unroll
    for (int k = 0; k < 8; ++k) {
        float v = acc[k];
        v += __shfl_xor(v, 8, 64);
        v += __shfl_xor(v, 16, 64);
        v += __shfl_xor(v, 32, 64);
        acc[k] = v;
    }
    if (sidx == 0) {
        const float inv = 1.f / fmaxf((float)(end - beg), 1.f);
        const size_t base = (size_t)n * 64 + cog * 8;
        const float4 r0 = *(const float4*)&Hroot[base];
        const float4 r1 = *(const float4*)&Hroot[base + 4];
        *(float4*)&outb[base] = make_float4(acc[0] * inv + r0.x, acc[1] * inv + r0.y,
                                            acc[2] * inv + r0.z, acc[3] * inv + r0.w);
        *(float4*)&outb[base + 4] = make_float4(acc[4] * inv + r1.x, acc[5] * inv + r1.y,
                                                acc[6] * inv + r1.z, acc[7] * inv + r1.w);
    }
}

// ---------------------------------------------------------------------------
// K5b: BN stats over outb.
// ---------------------------------------------------------------------------
__global__ __launch_bounds__(256) void stats_k(const float* __restrict__ outb,
                                               float* __restrict__ bnsum,
                                               float* __restrict__ bnssq) {
    __shared__ float red0[256], red1[256];
    const int t = threadIdx.x;
    const int co = t & 63;
    const int rg = blockIdx.x * 4 + (t >> 6);
    float s = 0.f, q = 0.f;
    for (int r = rg; r < NN; r += 512) {
        float v = outb[(size_t)r * 64 + co];
        s += v; q += v * v;
    }
    red0[t] = s; red1[t] = q;
    __syncthreads();
    if (t < 64) {
        s = red0[t] + red0[t + 64] + red0[t + 128] + red0[t + 192];
        q = red1[t] + red1[t + 64] + red1[t + 128] + red1[t + 192];
        atomicAdd(&bnsum[t], s);
        atomicAdd(&bnssq[t], q);
    }
}

// ---------------------------------------------------------------------------
// K6: BN + ELU, in place, float4.
// ---------------------------------------------------------------------------
__global__ __launch_bounds__(256) void finalize_kernel(float* __restrict__ outb,
                                                       const float* __restrict__ bnsum,
                                                       const float* __restrict__ bnssq,
                                                       const float* __restrict__ gamma,
                                                       const float* __restrict__ beta) {
    const int idx = blockIdx.x * 256 + threadIdx.x;
    const int total4 = NN * 64 / 4;
    if (idx >= total4) return;
    const int co0 = (idx & 15) * 4;
    float4 v = ((const float4*)outb)[idx];
    float o[4] = {v.x, v.y, v.z, v.w};
    #pragma unroll
    for (int j = 0; j < 4; ++j) {
        int co = co0 + j;
        float mean = bnsum[co] * (1.f / NN);
        float var  = bnssq[co] * (1.f / NN) - mean * mean;
        float sc = rsqrtf(var + EPS) * gamma[co];
        float sh = beta[co] - mean * sc;
        float y = o[j] * sc + sh;
        o[j] = (y > 0.f) ? y : expm1f(y);
    }
    ((float4*)outb)[idx] = make_float4(o[0], o[1], o[2], o[3]);
}

// ---------------------------------------------------------------------------
extern "C" void kernel_launch(void* const* d_in, const int* in_sizes, int n_in,
                              void* d_out, int out_size, void* d_ws, size_t ws_size,
                              hipStream_t stream) {
    const float* x     = (const float*)d_in[0];
    const float* attr  = (const float*)d_in[1];
    const float* W     = (const float*)d_in[2];
    const float* root  = (const float*)d_in[3];
    const float* gamma = (const float*)d_in[4];
    const float* beta  = (const float*)d_in[5];
    const int*   ei    = (const int*)d_in[6];
    float* outb = (float*)d_out;

    char* ws = (char*)d_ws;
    ushort* H2    = (ushort*)(ws);
    float*  Hroot = (float*)(ws + 51200000);
    int2*   recs  = (int2*)(ws + 64000000);
    int*    offs  = (int*)(ws + 70400000);
    int*    curs  = (int*)(ws + 70600064);
    int*    deg   = (int*)(ws + 70800064);
    int*    part  = (int*)(ws + 71000064);
    int*    partx = (int*)(ws + 71000192);
    float*  bnsum = (float*)(ws + 71000320);
    float*  bnssq = (float*)(ws + 71000576);
    ushort* WTg   = (ushort*)(ws + 71000832);

    // zero deg + part + partx + bnsum + bnssq (contiguous tail region)
    hipMemsetAsync(ws + 70800064, 0, 200768, stream);

    wt_prep<<<(9 * 4096 + 255) / 256, 256, 0, stream>>>(W, root, WTg);
    h_mfma<<<dim3(782, 9), 256, 0, stream>>>(x, WTg, H2, Hroot);
    count_k<<<(NE + 255) / 256, 256, 0, stream>>>(ei, deg);
    scan1<<<25, 256, 0, stream>>>(deg, offs, part);
    scan2<<<1, 64, 0, stream>>>(part, partx, offs);
    scan3<<<25, 256, 0, stream>>>(offs, partx, curs);
    scatter_k<<<(NE + 255) / 256, 256, 0, stream>>>(ei, attr, curs, recs);
    aggregate_k<<<(NN + 3) / 4, 256, 0, stream>>>(offs, recs, H2, Hroot, outb);
    stats_k<<<128, 256, 0, stream>>>(outb, bnsum, bnssq);
    finalize_kernel<<<(NN * 64 / 4 + 255) / 256, 256, 0, stream>>>(outb, bnsum, bnssq, gamma, beta);
}

// Round 6
// 288.243 us; speedup vs baseline: 1.3571x; 1.0156x over previous
//
#include <hip/hip_runtime.h>
#include <hip/hip_bf16.h>
#include <cstdint>
#include <cstddef>

#define NN 50000
#define NE 800000
#define EPS 1e-5f

typedef short bf16x8 __attribute__((ext_vector_type(8)));
typedef float f32x4  __attribute__((ext_vector_type(4)));
typedef float f32x2  __attribute__((ext_vector_type(2)));

// ---------------- ws layout (bytes) ----------------
// H2    :          0   51,200,000  ushort  H[n][s][co] bf16
// Hroot : 51,200,000   12,800,000  float   (x@root)[n][co]
// RECS  : 64,000,000    6,400,000  int2    {src, q3} dst-sorted
// OFFS  : 70,400,000      200,064  int     CSR offsets [NN+1]
// CURS  : 70,600,064      200,000  int     scatter cursors
// DEG   : 70,800,064      200,000  int     degree histogram
// PART  : 71,000,064          128  int     scan partials
// (hole):71,000,192          128  (unused)
// BNS   : 71,000,320          256  float   BN sum
// BNQ   : 71,000,576          256  float   BN sumsq
// WTG   : 71,000,832       73,728  ushort  WTg[s][co][ci] bf16 (s=8 is root)

static __device__ __forceinline__ ushort f2bf(float f) {
    __hip_bfloat16 h = __float2bfloat16(f);
    return *reinterpret_cast<ushort*>(&h);
}
static __device__ __forceinline__ float bf_lo(uint32_t u) {
    return __uint_as_float(u << 16);
}
static __device__ __forceinline__ float bf_hi(uint32_t u) {
    return __uint_as_float(u & 0xffff0000u);
}
static __device__ __forceinline__ uint32_t pack2(float a, float b) {
    return (uint32_t)f2bf(a) | ((uint32_t)f2bf(b) << 16);
}

// ---------------------------------------------------------------------------
// K0: transpose W (+root as s==8) to bf16 WTg[s][co][ci]. 72 KB, one-time.
// ---------------------------------------------------------------------------
__global__ __launch_bounds__(256) void wt_prep(const float* __restrict__ W,
                                               const float* __restrict__ root,
                                               ushort* __restrict__ WTg) {
    const int idx = blockIdx.x * 256 + threadIdx.x;      // [0, 9*4096)
    if (idx >= 9 * 4096) return;
    const int s  = idx >> 12;
    const int co = (idx >> 6) & 63;
    const int ci = idx & 63;
    const float v = (s < 8) ? W[s * 4096 + ci * 64 + co] : root[ci * 64 + co];
    WTg[idx] = f2bf(v);   // WTg[s][co][ci]
}

// ---------------------------------------------------------------------------
// K1: H2[n][s][co] = x[n] @ W[s] (bf16 out), s==8 -> Hroot (f32 out).
// MFMA 16x16x32 bf16. Grid (782, 2): y=0 -> s 0..4, y=1 -> s 5..8.
// XA staged ONCE per block; that half's WT tiles all resident in LDS (48KB).
// LDS XOR-swizzled so all frag reads are conflict-free b128.
// ---------------------------------------------------------------------------
__global__ __launch_bounds__(256) void h_mfma(const float* __restrict__ x,
                                              const ushort* __restrict__ WTg,
                                              ushort* __restrict__ H2,
                                              float* __restrict__ Hroot) {
    __shared__ __align__(16) ushort XA[64 * 64];       // 8 KB
    __shared__ __align__(16) ushort WT[5 * 64 * 64];   // 40 KB (<=5 s-tiles)
    const int n0 = blockIdx.x * 64;
    const int sbeg   = (blockIdx.y == 0) ? 0 : 5;
    const int scount = (blockIdx.y == 0) ? 5 : 4;
    const int t  = threadIdx.x;

    // stage XA: 512 b128 writes (node-major, 8 bf16 each), swizzled
    #pragma unroll
    for (int rep = 0; rep < 2; ++rep) {
        const int vt   = rep * 256 + t;
        const int row  = vt >> 3;          // node local 0..63
        const int col8 = vt & 7;
        const int n = n0 + row;
        uint4 u;
        if (n < NN) {
            const float4 v0 = *(const float4*)&x[(size_t)n * 64 + col8 * 8];
            const float4 v1 = *(const float4*)&x[(size_t)n * 64 + col8 * 8 + 4];
            u.x = pack2(v0.x, v0.y); u.y = pack2(v0.z, v0.w);
            u.z = pack2(v1.x, v1.y); u.w = pack2(v1.z, v1.w);
        } else {
            u = make_uint4(0, 0, 0, 0);
        }
        const int idx = (row * 64 + col8 * 8) ^ ((row & 7) << 3);
        *(uint4*)&XA[idx] = u;
    }
    // stage WT tiles [sbeg, sbeg+scount): b128 copies, swizzled
    const int nchunk = scount * 512;                   // uint4 chunks
    for (int c = t; c < nchunk; c += 256) {
        const int row  = c >> 3;           // local (slocal*64 + co)
        const int col8 = c & 7;
        const uint4 u = *(const uint4*)&WTg[(size_t)(sbeg * 64 + row) * 64 + col8 * 8];
        const int idx = (row * 64 + col8 * 8) ^ ((row & 7) << 3);
        *(uint4*)&WT[idx] = u;
    }
    __syncthreads();

    const int w    = t >> 6;
    const int lane = t & 63;
    const int mrow = lane & 15;     // A row / B col within tile
    const int kgrp = lane >> 4;     // k group (8 k each)
    const int swz  = (mrow & 7) << 3;
    const int arow = w * 16 + mrow;

    // A frags once (row&7 == mrow&7 since w*16 is a multiple of 8)
    const bf16x8 a0 = *(const bf16x8*)&XA[((arow * 64) + 0 * 32 + kgrp * 8) ^ swz];
    const bf16x8 a1 = *(const bf16x8*)&XA[((arow * 64) + 1 * 32 + kgrp * 8) ^ swz];

    for (int sl = 0; sl < scount; ++sl) {
        const int s = sbeg + sl;
        const ushort* wt = &WT[sl * 4096];
        f32x4 acc[4];
        #pragma unroll
        for (int ct = 0; ct < 4; ++ct) {
            acc[ct] = (f32x4){0.f, 0.f, 0.f, 0.f};
            const int brow = ct * 16 + mrow;
            const bf16x8 b0 = *(const bf16x8*)&wt[((brow * 64) + 0 * 32 + kgrp * 8) ^ swz];
            const bf16x8 b1 = *(const bf16x8*)&wt[((brow * 64) + 1 * 32 + kgrp * 8) ^ swz];
            acc[ct] = __builtin_amdgcn_mfma_f32_16x16x32_bf16(a0, b0, acc[ct], 0, 0, 0);
            acc[ct] = __builtin_amdgcn_mfma_f32_16x16x32_bf16(a1, b1, acc[ct], 0, 0, 0);
        }
        // store: C row (node) = kgrp*4 + r, col (co) = ct*16 + mrow
        #pragma unroll
        for (int ct = 0; ct < 4; ++ct) {
            const int co = ct * 16 + mrow;
            #pragma unroll
            for (int r = 0; r < 4; ++r) {
                const int n = n0 + w * 16 + kgrp * 4 + r;
                if (n < NN) {
                    if (s < 8) H2[(size_t)n * 512 + s * 64 + co] = f2bf(acc[ct][r]);
                    else       Hroot[(size_t)n * 64 + co] = acc[ct][r];
                }
            }
        }
    }
}

// ---------------------------------------------------------------------------
// K2: degree histogram
// ---------------------------------------------------------------------------
__global__ __launch_bounds__(256) void count_k(const int* __restrict__ ei,
                                               int* __restrict__ deg) {
    int e = blockIdx.x * 256 + threadIdx.x;
    if (e < NE) atomicAdd(&deg[ei[NE + e]], 1);
}

// ---------------------------------------------------------------------------
// K3a: block-local exclusive scan of deg -> offs, partials -> part
// ---------------------------------------------------------------------------
__global__ __launch_bounds__(256) void scan1(const int* __restrict__ deg,
                                             int* __restrict__ offs,
                                             int* __restrict__ part) {
    __shared__ int sh[256];
    const int b = blockIdx.x, t = threadIdx.x;
    const int base = b * 2048 + t * 8;
    int v[8]; int sum = 0;
    #pragma unroll
    for (int k = 0; k < 8; ++k) {
        int i = base + k;
        int d = (i < NN) ? deg[i] : 0;
        v[k] = sum; sum += d;
    }
    sh[t] = sum; __syncthreads();
    for (int off = 1; off < 256; off <<= 1) {
        int val = sh[t];
        int add = (t >= off) ? sh[t - off] : 0;
        __syncthreads();
        sh[t] = val + add;
        __syncthreads();
    }
    int excl = (t > 0) ? sh[t - 1] : 0;
    #pragma unroll
    for (int k = 0; k < 8; ++k) {
        int i = base + k;
        if (i < NN) offs[i] = excl + v[k];
    }
    if (t == 255) part[b] = sh[255];
}

// ---------------------------------------------------------------------------
// K3b: add block-prefix (computed inline from part[]), init cursors,
// write offs[NN].
// ---------------------------------------------------------------------------
__global__ __launch_bounds__(256) void scan3(int* __restrict__ offs,
                                             const int* __restrict__ part,
                                             int* __restrict__ curs) {
    const int b = blockIdx.x, t = threadIdx.x;
    int add = 0;
    for (int i = 0; i < b; ++i) add += part[i];
    if (b == 24 && t == 0) offs[NN] = add + part[24];
    #pragma unroll
    for (int k = 0; k < 8; ++k) {
        int i = b * 2048 + t * 8 + k;
        if (i < NN) { int o = offs[i] + add; offs[i] = o; curs[i] = o; }
    }
}

// ---------------------------------------------------------------------------
// K4: scatter edges: record = {src, q3}, q3 = 3x10-bit quantized fracs.
// ---------------------------------------------------------------------------
__global__ __launch_bounds__(256) void scatter_k(const int* __restrict__ ei,
                                                 const float* __restrict__ attr,
                                                 int* __restrict__ curs,
                                                 int2* __restrict__ recs) {
    int e = blockIdx.x * 256 + threadIdx.x;
    if (e >= NE) return;
    const int src = ei[e];
    const int dst = ei[NE + e];
    const float f0 = attr[(size_t)e * 3 + 0];
    const float f1 = attr[(size_t)e * 3 + 1];
    const float f2 = attr[(size_t)e * 3 + 2];
    const uint32_t q = (uint32_t)rintf(f0 * 1023.f)
                     | ((uint32_t)rintf(f1 * 1023.f) << 10)
                     | ((uint32_t)rintf(f2 * 1023.f) << 20);
    int p = atomicAdd(&curs[dst], 1);
    recs[p] = make_int2(src, (int)q);
}

// ---------------------------------------------------------------------------
// K5: gather-aggregate. One node per wave; lane l: s=l>>3, co=(l&7)*8..+8.
// f32x2 accumulators -> v_pk_fma_f32.
// ---------------------------------------------------------------------------
__global__ __launch_bounds__(256) void aggregate_k(const int* __restrict__ offs,
                                                   const int2* __restrict__ recs,
                                                   const ushort* __restrict__ H2,
                                                   const float* __restrict__ Hroot,
                                                   float* __restrict__ outb) {
    const int t = threadIdx.x, lane = t & 63, w = t >> 6;
    const int n = blockIdx.x * 4 + w;            // NN = 4*12500, no tail
    const int sidx = lane >> 3;
    const int cog  = lane & 7;
    const float sg0 = (sidx & 1) ? 1.f : -1.f, cc0 = (sidx & 1) ? 0.f : 1.f;
    const float sg1 = (sidx & 2) ? 1.f : -1.f, cc1 = (sidx & 2) ? 0.f : 1.f;
    const float sg2 = (sidx & 4) ? 1.f : -1.f, cc2 = (sidx & 4) ? 0.f : 1.f;
    const int beg = offs[n], end = offs[n + 1];
    const size_t loff = (size_t)(lane << 3);

    f32x2 acc2[4] = {(f32x2){0.f, 0.f}, (f32x2){0.f, 0.f},
                     (f32x2){0.f, 0.f}, (f32x2){0.f, 0.f}};

#define DECODE_W(qv, wv)                                                     \
    {                                                                        \
        const uint32_t q_ = (uint32_t)(qv);                                  \
        const float f0_ = (float)(q_ & 1023u) * (1.f / 1023.f);              \
        const float f1_ = (float)((q_ >> 10) & 1023u) * (1.f / 1023.f);      \
        const float f2_ = (float)((q_ >> 20) & 1023u) * (1.f / 1023.f);      \
        wv = (cc0 + sg0 * f0_) * ((cc1 + sg1 * f1_) * (cc2 + sg2 * f2_));    \
    }
#define ACCUM(wv, h)                                                         \
    {                                                                        \
        const f32x2 w2_ = {wv, wv};                                          \
        acc2[0] += w2_ * (f32x2){bf_lo((h).x), bf_hi((h).x)};                \
        acc2[1] += w2_ * (f32x2){bf_lo((h).y), bf_hi((h).y)};                \
        acc2[2] += w2_ * (f32x2){bf_lo((h).z), bf_hi((h).z)};                \
        acc2[3] += w2_ * (f32x2){bf_lo((h).w), bf_hi((h).w)};                \
    }

    int j = beg;
    for (; j + 3 < end; j += 4) {
        const int2 r0 = recs[j];
        const int2 r1 = recs[j + 1];
        const int2 r2 = recs[j + 2];
        const int2 r3 = recs[j + 3];
        const uint4 h0 = *(const uint4*)(H2 + (size_t)r0.x * 512 + loff);
        const uint4 h1 = *(const uint4*)(H2 + (size_t)r1.x * 512 + loff);
        const uint4 h2 = *(const uint4*)(H2 + (size_t)r2.x * 512 + loff);
        const uint4 h3 = *(const uint4*)(H2 + (size_t)r3.x * 512 + loff);
        float w0, w1, w2, w3;
        DECODE_W(r0.y, w0); DECODE_W(r1.y, w1);
        DECODE_W(r2.y, w2); DECODE_W(r3.y, w3);
        ACCUM(w0, h0); ACCUM(w1, h1); ACCUM(w2, h2); ACCUM(w3, h3);
    }
    for (; j < end; ++j) {
        const int2 r0 = recs[j];
        const uint4 h0 = *(const uint4*)(H2 + (size_t)r0.x * 512 + loff);
        float w0;
        DECODE_W(r0.y, w0);
        ACCUM(w0, h0);
    }
#undef DECODE_W
#undef ACCUM

    float accf[8] = {acc2[0].x, acc2[0].y, acc2[1].x, acc2[1].y,
                     acc2[2].x, acc2[2].y, acc2[3].x, acc2[3].y};
    #pragma unroll
    for (int k = 0; k < 8; ++k) {
        float v = accf[k];
        v += __shfl_xor(v, 8, 64);
        v += __shfl_xor(v, 16, 64);
        v += __shfl_xor(v, 32, 64);
        accf[k] = v;
    }
    if (sidx == 0) {
        const float inv = 1.f / fmaxf((float)(end - beg), 1.f);
        const size_t base = (size_t)n * 64 + cog * 8;
        const float4 r0 = *(const float4*)&Hroot[base];
        const float4 r1 = *(const float4*)&Hroot[base + 4];
        *(float4*)&outb[base] = make_float4(accf[0] * inv + r0.x, accf[1] * inv + r0.y,
                                            accf[2] * inv + r0.z, accf[3] * inv + r0.w);
        *(float4*)&outb[base + 4] = make_float4(accf[4] * inv + r1.x, accf[5] * inv + r1.y,
                                                accf[6] * inv + r1.z, accf[7] * inv + r1.w);
    }
}

// ---------------------------------------------------------------------------
// K5b: BN stats over outb. 128 blocks keeps per-address atomic count low.
// ---------------------------------------------------------------------------
__global__ __launch_bounds__(256) void stats_k(const float* __restrict__ outb,
                                               float* __restrict__ bnsum,
                                               float* __restrict__ bnssq) {
    __shared__ float red0[256], red1[256];
    const int t = threadIdx.x;
    const int co = t & 63;
    const int rg = blockIdx.x * 4 + (t >> 6);
    float s = 0.f, q = 0.f;
    for (int r = rg; r < NN; r += 512) {
        float v = outb[(size_t)r * 64 + co];
        s += v; q += v * v;
    }
    red0[t] = s; red1[t] = q;
    __syncthreads();
    if (t < 64) {
        s = red0[t] + red0[t + 64] + red0[t + 128] + red0[t + 192];
        q = red1[t] + red1[t + 64] + red1[t + 128] + red1[t + 192];
        atomicAdd(&bnsum[t], s);
        atomicAdd(&bnssq[t], q);
    }
}

// ---------------------------------------------------------------------------
// K6: BN + ELU, in place, float4.
// ---------------------------------------------------------------------------
__global__ __launch_bounds__(256) void finalize_kernel(float* __restrict__ outb,
                                                       const float* __restrict__ bnsum,
                                                       const float* __restrict__ bnssq,
                                                       const float* __restrict__ gamma,
                                                       const float* __restrict__ beta) {
    const int idx = blockIdx.x * 256 + threadIdx.x;
    const int total4 = NN * 64 / 4;
    if (idx >= total4) return;
    const int co0 = (idx & 15) * 4;
    float4 v = ((const float4*)outb)[idx];
    float o[4] = {v.x, v.y, v.z, v.w};
    #pragma unroll
    for (int j = 0; j < 4; ++j) {
        int co = co0 + j;
        float mean = bnsum[co] * (1.f / NN);
        float var  = bnssq[co] * (1.f / NN) - mean * mean;
        float sc = rsqrtf(var + EPS) * gamma[co];
        float sh = beta[co] - mean * sc;
        float y = o[j] * sc + sh;
        o[j] = (y > 0.f) ? y : expm1f(y);
    }
    ((float4*)outb)[idx] = make_float4(o[0], o[1], o[2], o[3]);
}

// ---------------------------------------------------------------------------
extern "C" void kernel_launch(void* const* d_in, const int* in_sizes, int n_in,
                              void* d_out, int out_size, void* d_ws, size_t ws_size,
                              hipStream_t stream) {
    const float* x     = (const float*)d_in[0];
    const float* attr  = (const float*)d_in[1];
    const float* W     = (const float*)d_in[2];
    const float* root  = (const float*)d_in[3];
    const float* gamma = (const float*)d_in[4];
    const float* beta  = (const float*)d_in[5];
    const int*   ei    = (const int*)d_in[6];
    float* outb = (float*)d_out;

    char* ws = (char*)d_ws;
    ushort* H2    = (ushort*)(ws);
    float*  Hroot = (float*)(ws + 51200000);
    int2*   recs  = (int2*)(ws + 64000000);
    int*    offs  = (int*)(ws + 70400000);
    int*    curs  = (int*)(ws + 70600064);
    int*    deg   = (int*)(ws + 70800064);
    int*    part  = (int*)(ws + 71000064);
    float*  bnsum = (float*)(ws + 71000320);
    float*  bnssq = (float*)(ws + 71000576);
    ushort* WTg   = (ushort*)(ws + 71000832);

    // zero deg + part + bn accumulators (contiguous tail region)
    hipMemsetAsync(ws + 70800064, 0, 200768, stream);

    wt_prep<<<(9 * 4096 + 255) / 256, 256, 0, stream>>>(W, root, WTg);
    h_mfma<<<dim3(782, 2), 256, 0, stream>>>(x, WTg, H2, Hroot);
    count_k<<<(NE + 255) / 256, 256, 0, stream>>>(ei, deg);
    scan1<<<25, 256, 0, stream>>>(deg, offs, part);
    scan3<<<25, 256, 0, stream>>>(offs, part, curs);
    scatter_k<<<(NE + 255) / 256, 256, 0, stream>>>(ei, attr, curs, recs);
    aggregate_k<<<NN / 4, 256, 0, stream>>>(offs, recs, H2, Hroot, outb);
    stats_k<<<128, 256, 0, stream>>>(outb, bnsum, bnssq);
    finalize_kernel<<<(NN * 64 / 4 + 255) / 256, 256, 0, stream>>>(outb, bnsum, bnssq, gamma, beta);
}

// Round 7
// 251.360 us; speedup vs baseline: 1.5563x; 1.1467x over previous
//
#include <hip/hip_runtime.h>
#include <hip/hip_bf16.h>
#include <cstdint>
#include <cstddef>

#define NN 50000
#define NE 800000
#define EPS 1e-5f

typedef short bf16x8 __attribute__((ext_vector_type(8)));
typedef float f32x4  __attribute__((ext_vector_type(4)));
typedef float f32x2  __attribute__((ext_vector_type(2)));

// ---------------- ws layout (bytes) ----------------
// H2    :          0   51,200,000  ushort  H[n][s][co] bf16
// Hroot : 51,200,000   12,800,000  float   (x@root)[n][co]
// RECS  : 64,000,000    6,400,000  int2    {src, q3} dst-sorted
// RANK  : 70,400,000    3,200,000  int     rank of edge within its dst
// OFFS  : 73,600,000      200,064  int     CSR offsets [NN+1]
// DEG   : 73,800,064      200,000  int     degree histogram      \
// PART  : 74,000,064          128  int     scan partials          | zeroed
// BNS   : 74,000,320          256  float   BN sum                 | together
// BNQ   : 74,000,576          256  float   BN sumsq              /
// WTG   : 74,000,832       73,728  ushort  WTg[s][co][ci] bf16 (s=8 is root)

static __device__ __forceinline__ ushort f2bf(float f) {
    __hip_bfloat16 h = __float2bfloat16(f);
    return *reinterpret_cast<ushort*>(&h);
}
static __device__ __forceinline__ float bf_lo(uint32_t u) {
    return __uint_as_float(u << 16);
}
static __device__ __forceinline__ float bf_hi(uint32_t u) {
    return __uint_as_float(u & 0xffff0000u);
}
static __device__ __forceinline__ uint32_t pack2(float a, float b) {
    return (uint32_t)f2bf(a) | ((uint32_t)f2bf(b) << 16);
}

// ---------------------------------------------------------------------------
// K0: fused wt_prep (blocks 0..143) + degree histogram w/ rank (blocks 144+).
// ---------------------------------------------------------------------------
__global__ __launch_bounds__(256) void prep_count_k(const float* __restrict__ W,
                                                    const float* __restrict__ root,
                                                    ushort* __restrict__ WTg,
                                                    const int* __restrict__ ei,
                                                    int* __restrict__ deg,
                                                    int* __restrict__ rank) {
    const int b = blockIdx.x;
    if (b < 144) {
        const int idx = b * 256 + threadIdx.x;           // [0, 9*4096)
        if (idx < 9 * 4096) {
            const int s  = idx >> 12;
            const int co = (idx >> 6) & 63;
            const int ci = idx & 63;
            const float v = (s < 8) ? W[s * 4096 + ci * 64 + co] : root[ci * 64 + co];
            WTg[idx] = f2bf(v);                          // WTg[s][co][ci]
        }
    } else {
        const int e = (b - 144) * 256 + threadIdx.x;
        if (e < NE) rank[e] = atomicAdd(&deg[ei[NE + e]], 1);
    }
}

// ---------------------------------------------------------------------------
// K1: H2[n][s][co] = x[n] @ W[s] (bf16 out), s==8 -> Hroot (f32 out).
// MFMA 16x16x32 bf16, SWAPPED operands: mfma(WT_frag, XA_frag) -> D has
// row-dim = co ((lane>>4)*4+reg), col-dim = node (lane&15) => each lane
// stores 4 consecutive co per output row: ushort4 / float4 stores.
// Grid (782, 2): y=0 -> s 0..4, y=1 -> s 5..8. XA staged once per block.
// ---------------------------------------------------------------------------
__global__ __launch_bounds__(256) void h_mfma(const float* __restrict__ x,
                                              const ushort* __restrict__ WTg,
                                              ushort* __restrict__ H2,
                                              float* __restrict__ Hroot) {
    __shared__ __align__(16) ushort XA[64 * 64];       // 8 KB
    __shared__ __align__(16) ushort WT[5 * 64 * 64];   // 40 KB (<=5 s-tiles)
    const int n0 = blockIdx.x * 64;
    const int sbeg   = (blockIdx.y == 0) ? 0 : 5;
    const int scount = (blockIdx.y == 0) ? 5 : 4;
    const int t  = threadIdx.x;

    // stage XA: 512 b128 writes (node-major, 8 bf16 each), swizzled
    #pragma unroll
    for (int rep = 0; rep < 2; ++rep) {
        const int vt   = rep * 256 + t;
        const int row  = vt >> 3;          // node local 0..63
        const int col8 = vt & 7;
        const int n = n0 + row;
        uint4 u;
        if (n < NN) {
            const float4 v0 = *(const float4*)&x[(size_t)n * 64 + col8 * 8];
            const float4 v1 = *(const float4*)&x[(size_t)n * 64 + col8 * 8 + 4];
            u.x = pack2(v0.x, v0.y); u.y = pack2(v0.z, v0.w);
            u.z = pack2(v1.x, v1.y); u.w = pack2(v1.z, v1.w);
        } else {
            u = make_uint4(0, 0, 0, 0);
        }
        const int idx = (row * 64 + col8 * 8) ^ ((row & 7) << 3);
        *(uint4*)&XA[idx] = u;
    }
    // stage WT tiles [sbeg, sbeg+scount): b128 copies, swizzled
    const int nchunk = scount * 512;                   // uint4 chunks
    for (int c = t; c < nchunk; c += 256) {
        const int row  = c >> 3;           // local (slocal*64 + co)
        const int col8 = c & 7;
        const uint4 u = *(const uint4*)&WTg[(size_t)(sbeg * 64 + row) * 64 + col8 * 8];
        const int idx = (row * 64 + col8 * 8) ^ ((row & 7) << 3);
        *(uint4*)&WT[idx] = u;
    }
    __syncthreads();

    const int w    = t >> 6;
    const int lane = t & 63;
    const int mrow = lane & 15;
    const int kgrp = lane >> 4;
    const int swz  = (mrow & 7) << 3;
    const int arow = w * 16 + mrow;
    const int n    = n0 + arow;            // output node this lane stores

    const bf16x8 a0 = *(const bf16x8*)&XA[((arow * 64) + 0 * 32 + kgrp * 8) ^ swz];
    const bf16x8 a1 = *(const bf16x8*)&XA[((arow * 64) + 1 * 32 + kgrp * 8) ^ swz];

    for (int sl = 0; sl < scount; ++sl) {
        const int s = sbeg + sl;
        const ushort* wt = &WT[sl * 4096];
        f32x4 acc[4];
        #pragma unroll
        for (int ct = 0; ct < 4; ++ct) {
            acc[ct] = (f32x4){0.f, 0.f, 0.f, 0.f};
            const int brow = ct * 16 + mrow;
            const bf16x8 b0 = *(const bf16x8*)&wt[((brow * 64) + 0 * 32 + kgrp * 8) ^ swz];
            const bf16x8 b1 = *(const bf16x8*)&wt[((brow * 64) + 1 * 32 + kgrp * 8) ^ swz];
            // swapped: row-dim = co (from WT frag), col-dim = node (from XA frag)
            acc[ct] = __builtin_amdgcn_mfma_f32_16x16x32_bf16(b0, a0, acc[ct], 0, 0, 0);
            acc[ct] = __builtin_amdgcn_mfma_f32_16x16x32_bf16(b1, a1, acc[ct], 0, 0, 0);
        }
        if (n < NN) {
            if (s < 8) {
                #pragma unroll
                for (int ct = 0; ct < 4; ++ct) {
                    ushort4 h4;
                    h4.x = f2bf(acc[ct][0]); h4.y = f2bf(acc[ct][1]);
                    h4.z = f2bf(acc[ct][2]); h4.w = f2bf(acc[ct][3]);
                    *(ushort4*)&H2[(size_t)n * 512 + s * 64 + ct * 16 + kgrp * 4] = h4;
                }
            } else {
                #pragma unroll
                for (int ct = 0; ct < 4; ++ct) {
                    *(float4*)&Hroot[(size_t)n * 64 + ct * 16 + kgrp * 4] =
                        make_float4(acc[ct][0], acc[ct][1], acc[ct][2], acc[ct][3]);
                }
            }
        }
    }
}

// ---------------------------------------------------------------------------
// K3a: block-local exclusive scan of deg -> offs, partials -> part
// ---------------------------------------------------------------------------
__global__ __launch_bounds__(256) void scan1(const int* __restrict__ deg,
                                             int* __restrict__ offs,
                                             int* __restrict__ part) {
    __shared__ int sh[256];
    const int b = blockIdx.x, t = threadIdx.x;
    const int base = b * 2048 + t * 8;
    int v[8]; int sum = 0;
    #pragma unroll
    for (int k = 0; k < 8; ++k) {
        int i = base + k;
        int d = (i < NN) ? deg[i] : 0;
        v[k] = sum; sum += d;
    }
    sh[t] = sum; __syncthreads();
    for (int off = 1; off < 256; off <<= 1) {
        int val = sh[t];
        int add = (t >= off) ? sh[t - off] : 0;
        __syncthreads();
        sh[t] = val + add;
        __syncthreads();
    }
    int excl = (t > 0) ? sh[t - 1] : 0;
    #pragma unroll
    for (int k = 0; k < 8; ++k) {
        int i = base + k;
        if (i < NN) offs[i] = excl + v[k];
    }
    if (t == 255) part[b] = sh[255];
}

// ---------------------------------------------------------------------------
// K3b: add block-prefix (computed inline from part[]), write offs[NN].
// ---------------------------------------------------------------------------
__global__ __launch_bounds__(256) void scan3(int* __restrict__ offs,
                                             const int* __restrict__ part) {
    const int b = blockIdx.x, t = threadIdx.x;
    int add = 0;
    for (int i = 0; i < b; ++i) add += part[i];
    if (b == 24 && t == 0) offs[NN] = add + part[24];
    #pragma unroll
    for (int k = 0; k < 8; ++k) {
        int i = b * 2048 + t * 8 + k;
        if (i < NN) offs[i] += add;
    }
}

// ---------------------------------------------------------------------------
// K4: scatter edges (NO atomics): p = offs[dst] + rank[e].
// record = {src, q3}, q3 = 3x10-bit quantized fracs.
// ---------------------------------------------------------------------------
__global__ __launch_bounds__(256) void scatter_k(const int* __restrict__ ei,
                                                 const float* __restrict__ attr,
                                                 const int* __restrict__ offs,
                                                 const int* __restrict__ rank,
                                                 int2* __restrict__ recs) {
    int e = blockIdx.x * 256 + threadIdx.x;
    if (e >= NE) return;
    const int src = ei[e];
    const int dst = ei[NE + e];
    const float f0 = attr[(size_t)e * 3 + 0];
    const float f1 = attr[(size_t)e * 3 + 1];
    const float f2 = attr[(size_t)e * 3 + 2];
    const uint32_t q = (uint32_t)rintf(f0 * 1023.f)
                     | ((uint32_t)rintf(f1 * 1023.f) << 10)
                     | ((uint32_t)rintf(f2 * 1023.f) << 20);
    const int p = offs[dst] + rank[e];
    recs[p] = make_int2(src, (int)q);
}

// ---------------------------------------------------------------------------
// K5: gather-aggregate. One node per wave; lane l: s=l>>3, co=(l&7)*8..+8.
// recs of group g+1 prefetched while H2 of group g is in flight.
// ---------------------------------------------------------------------------
__global__ __launch_bounds__(256) void aggregate_k(const int* __restrict__ offs,
                                                   const int2* __restrict__ recs,
                                                   const ushort* __restrict__ H2,
                                                   const float* __restrict__ Hroot,
                                                   float* __restrict__ outb) {
    const int t = threadIdx.x, lane = t & 63, w = t >> 6;
    const int n = blockIdx.x * 4 + w;            // NN = 4*12500, no tail
    const int sidx = lane >> 3;
    const int cog  = lane & 7;
    const float sg0 = (sidx & 1) ? 1.f : -1.f, cc0 = (sidx & 1) ? 0.f : 1.f;
    const float sg1 = (sidx & 2) ? 1.f : -1.f, cc1 = (sidx & 2) ? 0.f : 1.f;
    const float sg2 = (sidx & 4) ? 1.f : -1.f, cc2 = (sidx & 4) ? 0.f : 1.f;
    const int beg = offs[n], end = offs[n + 1];
    const int cnt = end - beg;
    const int2* rp = recs + beg;
    const size_t loff = (size_t)(lane << 3);

    f32x2 acc2[4] = {(f32x2){0.f, 0.f}, (f32x2){0.f, 0.f},
                     (f32x2){0.f, 0.f}, (f32x2){0.f, 0.f}};

#define DECODE_W(qv, wv)                                                     \
    {                                                                        \
        const uint32_t q_ = (uint32_t)(qv);                                  \
        const float f0_ = (float)(q_ & 1023u) * (1.f / 1023.f);              \
        const float f1_ = (float)((q_ >> 10) & 1023u) * (1.f / 1023.f);      \
        const float f2_ = (float)((q_ >> 20) & 1023u) * (1.f / 1023.f);      \
        wv = (cc0 + sg0 * f0_) * ((cc1 + sg1 * f1_) * (cc2 + sg2 * f2_));    \
    }
#define ACCUM(wv, h)                                                         \
    {                                                                        \
        const f32x2 w2_ = {wv, wv};                                          \
        acc2[0] += w2_ * (f32x2){bf_lo((h).x), bf_hi((h).x)};                \
        acc2[1] += w2_ * (f32x2){bf_lo((h).y), bf_hi((h).y)};                \
        acc2[2] += w2_ * (f32x2){bf_lo((h).z), bf_hi((h).z)};                \
        acc2[3] += w2_ * (f32x2){bf_lo((h).w), bf_hi((h).w)};                \
    }

    int j = 0;
    if (cnt >= 4) {
        int2 c0 = rp[0], c1 = rp[1], c2 = rp[2], c3 = rp[3];
        const int ng = cnt >> 2;
        const int m  = cnt - 1;
        for (int g = 0; g < ng; ++g) {
            const int b4 = (g + 1) * 4;
            // prefetch next recs group (clamped; wasted on last iter)
            const int2 p0 = rp[min(b4, m)];
            const int2 p1 = rp[min(b4 + 1, m)];
            const int2 p2 = rp[min(b4 + 2, m)];
            const int2 p3 = rp[min(b4 + 3, m)];
            const uint4 h0 = *(const uint4*)(H2 + (size_t)c0.x * 512 + loff);
            const uint4 h1 = *(const uint4*)(H2 + (size_t)c1.x * 512 + loff);
            const uint4 h2 = *(const uint4*)(H2 + (size_t)c2.x * 512 + loff);
            const uint4 h3 = *(const uint4*)(H2 + (size_t)c3.x * 512 + loff);
            float w0, w1, w2, w3;
            DECODE_W(c0.y, w0); DECODE_W(c1.y, w1);
            DECODE_W(c2.y, w2); DECODE_W(c3.y, w3);
            ACCUM(w0, h0); ACCUM(w1, h1); ACCUM(w2, h2); ACCUM(w3, h3);
            c0 = p0; c1 = p1; c2 = p2; c3 = p3;
        }
        j = ng * 4;
    }
    for (; j < cnt; ++j) {
        const int2 r0 = rp[j];
        const uint4 h0 = *(const uint4*)(H2 + (size_t)r0.x * 512 + loff);
        float w0;
        DECODE_W(r0.y, w0);
        ACCUM(w0, h0);
    }
#undef DECODE_W
#undef ACCUM

    float accf[8] = {acc2[0].x, acc2[0].y, acc2[1].x, acc2[1].y,
                     acc2[2].x, acc2[2].y, acc2[3].x, acc2[3].y};
    #pragma unroll
    for (int k = 0; k < 8; ++k) {
        float v = accf[k];
        v += __shfl_xor(v, 8, 64);
        v += __shfl_xor(v, 16, 64);
        v += __shfl_xor(v, 32, 64);
        accf[k] = v;
    }
    if (sidx == 0) {
        const float inv = 1.f / fmaxf((float)cnt, 1.f);
        const size_t base = (size_t)n * 64 + cog * 8;
        const float4 r0 = *(const float4*)&Hroot[base];
        const float4 r1 = *(const float4*)&Hroot[base + 4];
        *(float4*)&outb[base] = make_float4(accf[0] * inv + r0.x, accf[1] * inv + r0.y,
                                            accf[2] * inv + r0.z, accf[3] * inv + r0.w);
        *(float4*)&outb[base + 4] = make_float4(accf[4] * inv + r1.x, accf[5] * inv + r1.y,
                                                accf[6] * inv + r1.z, accf[7] * inv + r1.w);
    }
}

// ---------------------------------------------------------------------------
// K5b: BN stats over outb.
// ---------------------------------------------------------------------------
__global__ __launch_bounds__(256) void stats_k(const float* __restrict__ outb,
                                               float* __restrict__ bnsum,
                                               float* __restrict__ bnssq) {
    __shared__ float red0[256], red1[256];
    const int t = threadIdx.x;
    const int co = t & 63;
    const int rg = blockIdx.x * 4 + (t >> 6);
    float s = 0.f, q = 0.f;
    for (int r = rg; r < NN; r += 512) {
        float v = outb[(size_t)r * 64 + co];
        s += v; q += v * v;
    }
    red0[t] = s; red1[t] = q;
    __syncthreads();
    if (t < 64) {
        s = red0[t] + red0[t + 64] + red0[t + 128] + red0[t + 192];
        q = red1[t] + red1[t + 64] + red1[t + 128] + red1[t + 192];
        atomicAdd(&bnsum[t], s);
        atomicAdd(&bnssq[t], q);
    }
}

// ---------------------------------------------------------------------------
// K6: BN + ELU, in place, float4.
// ---------------------------------------------------------------------------
__global__ __launch_bounds__(256) void finalize_kernel(float* __restrict__ outb,
                                                       const float* __restrict__ bnsum,
                                                       const float* __restrict__ bnssq,
                                                       const float* __restrict__ gamma,
                                                       const float* __restrict__ beta) {
    const int idx = blockIdx.x * 256 + threadIdx.x;
    const int total4 = NN * 64 / 4;
    if (idx >= total4) return;
    const int co0 = (idx & 15) * 4;
    float4 v = ((const float4*)outb)[idx];
    float o[4] = {v.x, v.y, v.z, v.w};
    #pragma unroll
    for (int j = 0; j < 4; ++j) {
        int co = co0 + j;
        float mean = bnsum[co] * (1.f / NN);
        float var  = bnssq[co] * (1.f / NN) - mean * mean;
        float sc = rsqrtf(var + EPS) * gamma[co];
        float sh = beta[co] - mean * sc;
        float y = o[j] * sc + sh;
        o[j] = (y > 0.f) ? y : expm1f(y);
    }
    ((float4*)outb)[idx] = make_float4(o[0], o[1], o[2], o[3]);
}

// ---------------------------------------------------------------------------
extern "C" void kernel_launch(void* const* d_in, const int* in_sizes, int n_in,
                              void* d_out, int out_size, void* d_ws, size_t ws_size,
                              hipStream_t stream) {
    const float* x     = (const float*)d_in[0];
    const float* attr  = (const float*)d_in[1];
    const float* W     = (const float*)d_in[2];
    const float* root  = (const float*)d_in[3];
    const float* gamma = (const float*)d_in[4];
    const float* beta  = (const float*)d_in[5];
    const int*   ei    = (const int*)d_in[6];
    float* outb = (float*)d_out;

    char* ws = (char*)d_ws;
    ushort* H2    = (ushort*)(ws);
    float*  Hroot = (float*)(ws + 51200000);
    int2*   recs  = (int2*)(ws + 64000000);
    int*    rank  = (int*)(ws + 70400000);
    int*    offs  = (int*)(ws + 73600000);
    int*    deg   = (int*)(ws + 73800064);
    int*    part  = (int*)(ws + 74000064);
    float*  bnsum = (float*)(ws + 74000320);
    float*  bnssq = (float*)(ws + 74000576);
    ushort* WTg   = (ushort*)(ws + 74000832);

    // zero deg + part + bn accumulators (contiguous tail region)
    hipMemsetAsync(ws + 73800064, 0, 200768, stream);

    prep_count_k<<<144 + (NE + 255) / 256, 256, 0, stream>>>(W, root, WTg, ei, deg, rank);
    h_mfma<<<dim3(782, 2), 256, 0, stream>>>(x, WTg, H2, Hroot);
    scan1<<<25, 256, 0, stream>>>(deg, offs, part);
    scan3<<<25, 256, 0, stream>>>(offs, part);
    scatter_k<<<(NE + 255) / 256, 256, 0, stream>>>(ei, attr, offs, rank, recs);
    aggregate_k<<<NN / 4, 256, 0, stream>>>(offs, recs, H2, Hroot, outb);
    stats_k<<<128, 256, 0, stream>>>(outb, bnsum, bnssq);
    finalize_kernel<<<(NN * 64 / 4 + 255) / 256, 256, 0, stream>>>(outb, bnsum, bnssq, gamma, beta);
}

// Round 8
// 228.685 us; speedup vs baseline: 1.7106x; 1.0992x over previous
//
#include <hip/hip_runtime.h>
#include <hip/hip_bf16.h>
#include <cstdint>
#include <cstddef>

#define NN 50000
#define NE 800000
#define EPS 1e-5f

typedef short bf16x8 __attribute__((ext_vector_type(8)));
typedef float f32x4  __attribute__((ext_vector_type(4)));
typedef float f32x2  __attribute__((ext_vector_type(2)));

// ---------------- ws layout (bytes) ----------------
// H2    :          0   51,200,000  ushort  H[n][s][co] bf16
// Hroot : 51,200,000   12,800,000  float   (x@root)[n][co]
// RECS  : 64,000,000    6,400,000  int2    {src, q3} dst-sorted
// RANK  : 70,400,000    3,200,000  int     rank of edge within its dst
// OFFS  : 73,600,000      200,000  int     block-local CSR offsets [NN]
// DEG   : 73,800,000      200,000  int     degree histogram      \
// PART  : 74,000,000          128  int     scan partials          | zeroed
// BNPS  : 74,000,128       16,384  float   BN sum partials [64][64]   |
// BNPQ  : 74,016,512       16,384  float   BN ssq partials [64][64]  /

#define NB_MFMA 1564   // 782 x 2 halves
#define NB_CNT  3125   // ceil(NE/256)

static __device__ __forceinline__ ushort f2bf(float f) {
    __hip_bfloat16 h = __float2bfloat16(f);
    return *reinterpret_cast<ushort*>(&h);
}
static __device__ __forceinline__ float bf_lo(uint32_t u) {
    return __uint_as_float(u << 16);
}
static __device__ __forceinline__ float bf_hi(uint32_t u) {
    return __uint_as_float(u & 0xffff0000u);
}
static __device__ __forceinline__ uint32_t pack2(float a, float b) {
    return (uint32_t)f2bf(a) | ((uint32_t)f2bf(b) << 16);
}

// ---------------------------------------------------------------------------
// K1 (fused): blocks [0,1564): H2/Hroot MFMA GEMM (W transposed inline from
// f32 global). blocks [1564, 1564+3125): degree histogram + per-edge rank.
// ---------------------------------------------------------------------------
__global__ __launch_bounds__(256) void fused_mfma_count(
        const float* __restrict__ x, const float* __restrict__ W,
        const float* __restrict__ root, const int* __restrict__ ei,
        ushort* __restrict__ H2, float* __restrict__ Hroot,
        int* __restrict__ deg, int* __restrict__ rank) {
    __shared__ __align__(16) ushort XA[64 * 64];       // 8 KB
    __shared__ __align__(16) ushort WT[5 * 64 * 64];   // 40 KB
    const int t = threadIdx.x;
    const int b = blockIdx.x;

    if (b >= NB_MFMA) {                    // ---- count path ----
        const int e = (b - NB_MFMA) * 256 + t;
        if (e < NE) rank[e] = atomicAdd(&deg[ei[NE + e]], 1);
        return;
    }

    // ---- MFMA path ----
    const int bx   = (b < 782) ? b : b - 782;
    const int half = (b < 782) ? 0 : 1;
    const int n0 = bx * 64;
    const int sbeg   = half ? 5 : 0;
    const int scount = half ? 4 : 5;

    // stage XA[node][ci] bf16, XOR-swizzled, b128 writes
    #pragma unroll
    for (int rep = 0; rep < 2; ++rep) {
        const int vt   = rep * 256 + t;
        const int row  = vt >> 3;          // node local 0..63
        const int col8 = vt & 7;
        const int n = n0 + row;
        uint4 u;
        if (n < NN) {
            const float4 v0 = *(const float4*)&x[(size_t)n * 64 + col8 * 8];
            const float4 v1 = *(const float4*)&x[(size_t)n * 64 + col8 * 8 + 4];
            u.x = pack2(v0.x, v0.y); u.y = pack2(v0.z, v0.w);
            u.z = pack2(v1.x, v1.y); u.w = pack2(v1.z, v1.w);
        } else {
            u = make_uint4(0, 0, 0, 0);
        }
        const int idx = (row * 64 + col8 * 8) ^ ((row & 7) << 3);
        *(uint4*)&XA[idx] = u;
    }
    // stage WT[co][ci] bf16 swizzled, transposing f32 W[s][ci][co] on the fly
    for (int sl = 0; sl < scount; ++sl) {
        const int s = sbeg + sl;
        const float* wsrc = (s < 8) ? (W + s * 4096) : root;
        for (int c = t; c < 4096; c += 256) {
            const int co = c & 63, ci = c >> 6;        // coalesced over co
            WT[sl * 4096 + ((co * 64 + ci) ^ ((co & 7) << 3))] = f2bf(wsrc[ci * 64 + co]);
        }
    }
    __syncthreads();

    const int w    = t >> 6;
    const int lane = t & 63;
    const int mrow = lane & 15;
    const int kgrp = lane >> 4;
    const int swz  = (mrow & 7) << 3;
    const int arow = w * 16 + mrow;
    const int n    = n0 + arow;

    const bf16x8 a0 = *(const bf16x8*)&XA[((arow * 64) + 0 * 32 + kgrp * 8) ^ swz];
    const bf16x8 a1 = *(const bf16x8*)&XA[((arow * 64) + 1 * 32 + kgrp * 8) ^ swz];

    for (int sl = 0; sl < scount; ++sl) {
        const int s = sbeg + sl;
        const ushort* wt = &WT[sl * 4096];
        f32x4 acc[4];
        #pragma unroll
        for (int ct = 0; ct < 4; ++ct) {
            acc[ct] = (f32x4){0.f, 0.f, 0.f, 0.f};
            const int brow = ct * 16 + mrow;
            const bf16x8 b0 = *(const bf16x8*)&wt[((brow * 64) + 0 * 32 + kgrp * 8) ^ swz];
            const bf16x8 b1 = *(const bf16x8*)&wt[((brow * 64) + 1 * 32 + kgrp * 8) ^ swz];
            // swapped operands: output row-dim = co, col-dim = node
            acc[ct] = __builtin_amdgcn_mfma_f32_16x16x32_bf16(b0, a0, acc[ct], 0, 0, 0);
            acc[ct] = __builtin_amdgcn_mfma_f32_16x16x32_bf16(b1, a1, acc[ct], 0, 0, 0);
        }
        if (n < NN) {
            if (s < 8) {
                #pragma unroll
                for (int ct = 0; ct < 4; ++ct) {
                    ushort4 h4;
                    h4.x = f2bf(acc[ct][0]); h4.y = f2bf(acc[ct][1]);
                    h4.z = f2bf(acc[ct][2]); h4.w = f2bf(acc[ct][3]);
                    *(ushort4*)&H2[(size_t)n * 512 + s * 64 + ct * 16 + kgrp * 4] = h4;
                }
            } else {
                #pragma unroll
                for (int ct = 0; ct < 4; ++ct) {
                    *(float4*)&Hroot[(size_t)n * 64 + ct * 16 + kgrp * 4] =
                        make_float4(acc[ct][0], acc[ct][1], acc[ct][2], acc[ct][3]);
                }
            }
        }
    }
}

// ---------------------------------------------------------------------------
// K2: block-local exclusive scan of deg -> offs, block sums -> part[25]
// ---------------------------------------------------------------------------
__global__ __launch_bounds__(256) void scan1(const int* __restrict__ deg,
                                             int* __restrict__ offs,
                                             int* __restrict__ part) {
    __shared__ int sh[256];
    const int b = blockIdx.x, t = threadIdx.x;
    const int base = b * 2048 + t * 8;
    int v[8]; int sum = 0;
    #pragma unroll
    for (int k = 0; k < 8; ++k) {
        int i = base + k;
        int d = (i < NN) ? deg[i] : 0;
        v[k] = sum; sum += d;
    }
    sh[t] = sum; __syncthreads();
    for (int off = 1; off < 256; off <<= 1) {
        int val = sh[t];
        int add = (t >= off) ? sh[t - off] : 0;
        __syncthreads();
        sh[t] = val + add;
        __syncthreads();
    }
    int excl = (t > 0) ? sh[t - 1] : 0;
    #pragma unroll
    for (int k = 0; k < 8; ++k) {
        int i = base + k;
        if (i < NN) offs[i] = excl + v[k];
    }
    if (t == 255) part[b] = sh[255];
}

// ---------------------------------------------------------------------------
// K3: scatter edges (no atomics): p = offs[dst] + ppre[dst>>11] + rank[e].
// record = {src, q3}, q3 = 3x10-bit quantized fracs.
// ---------------------------------------------------------------------------
__global__ __launch_bounds__(256) void scatter_k(const int* __restrict__ ei,
                                                 const float* __restrict__ attr,
                                                 const int* __restrict__ offs,
                                                 const int* __restrict__ part,
                                                 const int* __restrict__ rank,
                                                 int2* __restrict__ recs) {
    __shared__ int pp[25];
    const int t = threadIdx.x;
    if (t < 25) pp[t] = part[t];
    __syncthreads();
    if (t == 0) {
        int s = 0;
        #pragma unroll
        for (int i = 0; i < 25; ++i) { int v = pp[i]; pp[i] = s; s += v; }
    }
    __syncthreads();
    int e = blockIdx.x * 256 + t;
    if (e >= NE) return;
    const int src = ei[e];
    const int dst = ei[NE + e];
    const float f0 = attr[(size_t)e * 3 + 0];
    const float f1 = attr[(size_t)e * 3 + 1];
    const float f2 = attr[(size_t)e * 3 + 2];
    const uint32_t q = (uint32_t)rintf(f0 * 1023.f)
                     | ((uint32_t)rintf(f1 * 1023.f) << 10)
                     | ((uint32_t)rintf(f2 * 1023.f) << 20);
    const int p = offs[dst] + pp[dst >> 11] + rank[e];
    recs[p] = make_int2(src, (int)q);
}

// ---------------------------------------------------------------------------
// K4: gather-aggregate + fused BN partials. One node per wave.
// lane l: s=l>>3, co=(l&7)*8..+8. beg = offs[n]+ppre, cnt = deg[n].
// ---------------------------------------------------------------------------
__global__ __launch_bounds__(256) void aggregate_k(const int* __restrict__ offs,
                                                   const int* __restrict__ part,
                                                   const int* __restrict__ deg,
                                                   const int2* __restrict__ recs,
                                                   const ushort* __restrict__ H2,
                                                   const float* __restrict__ Hroot,
                                                   float* __restrict__ outb,
                                                   float* __restrict__ bnps,
                                                   float* __restrict__ bnpq) {
    __shared__ int pp[25];
    __shared__ float red_s[4][64], red_q[4][64];
    const int t = threadIdx.x, lane = t & 63, w = t >> 6;
    if (t < 25) pp[t] = part[t];
    __syncthreads();
    if (t == 0) {
        int s = 0;
        #pragma unroll
        for (int i = 0; i < 25; ++i) { int v = pp[i]; pp[i] = s; s += v; }
    }
    __syncthreads();

    const int n = blockIdx.x * 4 + w;            // NN = 4*12500, no tail
    const int sidx = lane >> 3;
    const int cog  = lane & 7;
    const float sg0 = (sidx & 1) ? 1.f : -1.f, cc0 = (sidx & 1) ? 0.f : 1.f;
    const float sg1 = (sidx & 2) ? 1.f : -1.f, cc1 = (sidx & 2) ? 0.f : 1.f;
    const float sg2 = (sidx & 4) ? 1.f : -1.f, cc2 = (sidx & 4) ? 0.f : 1.f;
    const int cnt = deg[n];
    const int beg = offs[n] + pp[n >> 11];
    const int2* rp = recs + beg;
    const size_t loff = (size_t)(lane << 3);

    f32x2 acc2[4] = {(f32x2){0.f, 0.f}, (f32x2){0.f, 0.f},
                     (f32x2){0.f, 0.f}, (f32x2){0.f, 0.f}};

#define DECODE_W(qv, wv)                                                     \
    {                                                                        \
        const uint32_t q_ = (uint32_t)(qv);                                  \
        const float f0_ = (float)(q_ & 1023u) * (1.f / 1023.f);              \
        const float f1_ = (float)((q_ >> 10) & 1023u) * (1.f / 1023.f);      \
        const float f2_ = (float)((q_ >> 20) & 1023u) * (1.f / 1023.f);      \
        wv = (cc0 + sg0 * f0_) * ((cc1 + sg1 * f1_) * (cc2 + sg2 * f2_));    \
    }
#define ACCUM(wv, h)                                                         \
    {                                                                        \
        const f32x2 w2_ = {wv, wv};                                          \
        acc2[0] += w2_ * (f32x2){bf_lo((h).x), bf_hi((h).x)};                \
        acc2[1] += w2_ * (f32x2){bf_lo((h).y), bf_hi((h).y)};                \
        acc2[2] += w2_ * (f32x2){bf_lo((h).z), bf_hi((h).z)};                \
        acc2[3] += w2_ * (f32x2){bf_lo((h).w), bf_hi((h).w)};                \
    }

    int j = 0;
    for (; j + 3 < cnt; j += 4) {
        const int2 r0 = rp[j];
        const int2 r1 = rp[j + 1];
        const int2 r2 = rp[j + 2];
        const int2 r3 = rp[j + 3];
        const uint4 h0 = *(const uint4*)(H2 + (size_t)r0.x * 512 + loff);
        const uint4 h1 = *(const uint4*)(H2 + (size_t)r1.x * 512 + loff);
        const uint4 h2 = *(const uint4*)(H2 + (size_t)r2.x * 512 + loff);
        const uint4 h3 = *(const uint4*)(H2 + (size_t)r3.x * 512 + loff);
        float w0, w1, w2, w3;
        DECODE_W(r0.y, w0); DECODE_W(r1.y, w1);
        DECODE_W(r2.y, w2); DECODE_W(r3.y, w3);
        ACCUM(w0, h0); ACCUM(w1, h1); ACCUM(w2, h2); ACCUM(w3, h3);
    }
    for (; j < cnt; ++j) {
        const int2 r0 = rp[j];
        const uint4 h0 = *(const uint4*)(H2 + (size_t)r0.x * 512 + loff);
        float w0;
        DECODE_W(r0.y, w0);
        ACCUM(w0, h0);
    }
#undef DECODE_W
#undef ACCUM

    float accf[8] = {acc2[0].x, acc2[0].y, acc2[1].x, acc2[1].y,
                     acc2[2].x, acc2[2].y, acc2[3].x, acc2[3].y};
    #pragma unroll
    for (int k = 0; k < 8; ++k) {
        float v = accf[k];
        v += __shfl_xor(v, 8, 64);
        v += __shfl_xor(v, 16, 64);
        v += __shfl_xor(v, 32, 64);
        accf[k] = v;
    }
    if (sidx == 0) {
        const float inv = 1.f / fmaxf((float)cnt, 1.f);
        const size_t base = (size_t)n * 64 + cog * 8;
        const float4 r0 = *(const float4*)&Hroot[base];
        const float4 r1 = *(const float4*)&Hroot[base + 4];
        float vv[8];
        vv[0] = accf[0] * inv + r0.x; vv[1] = accf[1] * inv + r0.y;
        vv[2] = accf[2] * inv + r0.z; vv[3] = accf[3] * inv + r0.w;
        vv[4] = accf[4] * inv + r1.x; vv[5] = accf[5] * inv + r1.y;
        vv[6] = accf[6] * inv + r1.z; vv[7] = accf[7] * inv + r1.w;
        *(float4*)&outb[base]     = make_float4(vv[0], vv[1], vv[2], vv[3]);
        *(float4*)&outb[base + 4] = make_float4(vv[4], vv[5], vv[6], vv[7]);
        #pragma unroll
        for (int k = 0; k < 8; ++k) {
            red_s[w][cog * 8 + k] = vv[k];
            red_q[w][cog * 8 + k] = vv[k] * vv[k];
        }
    }
    __syncthreads();
    if (t < 64) {
        const float s = red_s[0][t] + red_s[1][t] + red_s[2][t] + red_s[3][t];
        const float q = red_q[0][t] + red_q[1][t] + red_q[2][t] + red_q[3][t];
        const int slot = (blockIdx.x & 63) * 64 + t;
        atomicAdd(&bnps[slot], s);
        atomicAdd(&bnpq[slot], q);
    }
}

// ---------------------------------------------------------------------------
// K5: BN + ELU. Stats preamble reduces the 64-slot partials per block.
// Grid-stride over float4s, 256 blocks.
// ---------------------------------------------------------------------------
__global__ __launch_bounds__(256) void finalize_kernel(float* __restrict__ outb,
                                                       const float* __restrict__ bnps,
                                                       const float* __restrict__ bnpq,
                                                       const float* __restrict__ gamma,
                                                       const float* __restrict__ beta) {
    __shared__ float sc_sh[64], sh_sh[64];
    const int t = threadIdx.x;
    if (t < 64) {
        float s = 0.f, q = 0.f;
        for (int k = 0; k < 64; ++k) { s += bnps[k * 64 + t]; q += bnpq[k * 64 + t]; }
        const float mean = s * (1.f / NN);
        const float var  = q * (1.f / NN) - mean * mean;
        const float sc = rsqrtf(var + EPS) * gamma[t];
        sc_sh[t] = sc;
        sh_sh[t] = beta[t] - mean * sc;
    }
    __syncthreads();
    const int total4 = NN * 16;
    for (int idx = blockIdx.x * 256 + t; idx < total4; idx += gridDim.x * 256) {
        float4 v = ((const float4*)outb)[idx];
        const int co0 = (idx & 15) * 4;
        float o[4] = {v.x, v.y, v.z, v.w};
        #pragma unroll
        for (int j = 0; j < 4; ++j) {
            const float y = o[j] * sc_sh[co0 + j] + sh_sh[co0 + j];
            o[j] = (y > 0.f) ? y : expm1f(y);
        }
        ((float4*)outb)[idx] = make_float4(o[0], o[1], o[2], o[3]);
    }
}

// ---------------------------------------------------------------------------
extern "C" void kernel_launch(void* const* d_in, const int* in_sizes, int n_in,
                              void* d_out, int out_size, void* d_ws, size_t ws_size,
                              hipStream_t stream) {
    const float* x     = (const float*)d_in[0];
    const float* attr  = (const float*)d_in[1];
    const float* W     = (const float*)d_in[2];
    const float* root  = (const float*)d_in[3];
    const float* gamma = (const float*)d_in[4];
    const float* beta  = (const float*)d_in[5];
    const int*   ei    = (const int*)d_in[6];
    float* outb = (float*)d_out;

    char* ws = (char*)d_ws;
    ushort* H2    = (ushort*)(ws);
    float*  Hroot = (float*)(ws + 51200000);
    int2*   recs  = (int2*)(ws + 64000000);
    int*    rank  = (int*)(ws + 70400000);
    int*    offs  = (int*)(ws + 73600000);
    int*    deg   = (int*)(ws + 73800000);
    int*    part  = (int*)(ws + 74000000);
    float*  bnps  = (float*)(ws + 74000128);
    float*  bnpq  = (float*)(ws + 74016512);

    // zero deg + part + bn partials (contiguous tail region)
    hipMemsetAsync(ws + 73800000, 0, 232896, stream);

    fused_mfma_count<<<NB_MFMA + NB_CNT, 256, 0, stream>>>(x, W, root, ei, H2, Hroot, deg, rank);
    scan1<<<25, 256, 0, stream>>>(deg, offs, part);
    scatter_k<<<NB_CNT, 256, 0, stream>>>(ei, attr, offs, part, rank, recs);
    aggregate_k<<<NN / 4, 256, 0, stream>>>(offs, part, deg, recs, H2, Hroot, outb, bnps, bnpq);
    finalize_kernel<<<256, 256, 0, stream>>>(outb, bnps, bnpq, gamma, beta);
}

// Round 9
// 175.333 us; speedup vs baseline: 2.2311x; 1.3043x over previous
//
#include <hip/hip_runtime.h>
#include <hip/hip_bf16.h>
#include <cstdint>
#include <cstddef>

#define NN 50000
#define NE 800000
#define EPS 1e-5f

typedef short bf16x8 __attribute__((ext_vector_type(8)));
typedef float f32x4  __attribute__((ext_vector_type(4)));
typedef float f32x2  __attribute__((ext_vector_type(2)));

// ---------------- ws layout (bytes) ----------------
// H8    :          0   25,600,000  uchar   H[n][s][co] fp8 e4m3
// Hroot : 25,600,000   12,800,000  float   (x@root)[n][co]
// RECS  : 38,400,000    6,400,000  int2    {src, q3} dst-sorted
// RANK  : 44,800,000    3,200,000  int     rank of edge within its dst
// OFFS  : 48,000,000      200,000  int     block-local CSR offsets [NN]
// DEG   : 48,200,000      200,000  int     degree histogram      \
// PART  : 48,400,000          128  int     scan partials          | zeroed
// BNPS  : 48,400,128       16,384  float   BN sum partials        | together
// BNPQ  : 48,416,512       16,384  float   BN ssq partials       /
// WTG   : 48,432,896       73,728  ushort  WTg[s][co][ci] bf16 (s=8 is root)

#define NB_WT   144    // 9*4096/256
#define NB_CNT  3125   // ceil(NE/256)
#define NB_MFMA 1564   // 782 x 2 halves
#define NB_SCAN 25

static __device__ __forceinline__ ushort f2bf(float f) {
    __hip_bfloat16 h = __float2bfloat16(f);
    return *reinterpret_cast<ushort*>(&h);
}
static __device__ __forceinline__ uint32_t pack2(float a, float b) {
    return (uint32_t)f2bf(a) | ((uint32_t)f2bf(b) << 16);
}

// ---------------------------------------------------------------------------
// K0 (fused): blocks [0,144): W(+root) transpose to bf16 WTg[s][co][ci].
//             blocks [144, 144+3125): degree histogram + per-edge rank.
// ---------------------------------------------------------------------------
__global__ __launch_bounds__(256) void prep_count_k(const float* __restrict__ W,
                                                    const float* __restrict__ root,
                                                    ushort* __restrict__ WTg,
                                                    const int* __restrict__ ei,
                                                    int* __restrict__ deg,
                                                    int* __restrict__ rank) {
    const int b = blockIdx.x;
    if (b < NB_WT) {
        const int idx = b * 256 + threadIdx.x;           // [0, 9*4096)
        const int s  = idx >> 12;
        const int co = (idx >> 6) & 63;
        const int ci = idx & 63;
        const float v = (s < 8) ? W[s * 4096 + ci * 64 + co] : root[ci * 64 + co];
        WTg[idx] = f2bf(v);                              // WTg[s][co][ci]
    } else {
        const int e = (b - NB_WT) * 256 + threadIdx.x;
        if (e < NE) rank[e] = atomicAdd(&deg[ei[NE + e]], 1);
    }
}

// ---------------------------------------------------------------------------
// K1 (fused): blocks [0,1564): MFMA GEMM -> H8 (fp8) / Hroot (f32).
//             blocks [1564,1589): scan1 (block-local excl scan of deg).
// MFMA 16x16x32 bf16, swapped operands (D row-dim = co, col-dim = node).
// ---------------------------------------------------------------------------
__global__ __launch_bounds__(256) void mfma_scan_k(
        const float* __restrict__ x, const ushort* __restrict__ WTg,
        uint8_t* __restrict__ H8, float* __restrict__ Hroot,
        const int* __restrict__ deg, int* __restrict__ offs,
        int* __restrict__ part) {
    __shared__ __align__(16) ushort XA[64 * 64];       // 8 KB
    __shared__ __align__(16) ushort WT[5 * 64 * 64];   // 40 KB
    __shared__ int sh[256];
    const int t = threadIdx.x;
    const int b = blockIdx.x;

    if (b >= NB_MFMA) {                    // ---- scan path ----
        const int sb = b - NB_MFMA;
        const int base = sb * 2048 + t * 8;
        int v[8]; int sum = 0;
        #pragma unroll
        for (int k = 0; k < 8; ++k) {
            int i = base + k;
            int d = (i < NN) ? deg[i] : 0;
            v[k] = sum; sum += d;
        }
        sh[t] = sum; __syncthreads();
        for (int off = 1; off < 256; off <<= 1) {
            int val = sh[t];
            int add = (t >= off) ? sh[t - off] : 0;
            __syncthreads();
            sh[t] = val + add;
            __syncthreads();
        }
        int excl = (t > 0) ? sh[t - 1] : 0;
        #pragma unroll
        for (int k = 0; k < 8; ++k) {
            int i = base + k;
            if (i < NN) offs[i] = excl + v[k];
        }
        if (t == 255) part[sb] = sh[255];
        return;
    }

    // ---- MFMA path ----
    const int bx   = (b < 782) ? b : b - 782;
    const int half = (b < 782) ? 0 : 1;
    const int n0 = bx * 64;
    const int sbeg   = half ? 5 : 0;
    const int scount = half ? 4 : 5;

    // stage XA[node][ci] bf16, XOR-swizzled, b128 writes
    #pragma unroll
    for (int rep = 0; rep < 2; ++rep) {
        const int vt   = rep * 256 + t;
        const int row  = vt >> 3;          // node local 0..63
        const int col8 = vt & 7;
        const int n = n0 + row;
        uint4 u;
        if (n < NN) {
            const float4 v0 = *(const float4*)&x[(size_t)n * 64 + col8 * 8];
            const float4 v1 = *(const float4*)&x[(size_t)n * 64 + col8 * 8 + 4];
            u.x = pack2(v0.x, v0.y); u.y = pack2(v0.z, v0.w);
            u.z = pack2(v1.x, v1.y); u.w = pack2(v1.z, v1.w);
        } else {
            u = make_uint4(0, 0, 0, 0);
        }
        const int idx = (row * 64 + col8 * 8) ^ ((row & 7) << 3);
        *(uint4*)&XA[idx] = u;
    }
    // stage WT tiles from WTg: b128 copies, swizzled
    const int nchunk = scount * 512;                   // uint4 chunks
    for (int c = t; c < nchunk; c += 256) {
        const int row  = c >> 3;           // slocal*64 + co
        const int col8 = c & 7;
        const uint4 u = *(const uint4*)&WTg[(size_t)(sbeg * 64 + row) * 64 + col8 * 8];
        const int idx = (row * 64 + col8 * 8) ^ ((row & 7) << 3);
        *(uint4*)&WT[idx] = u;
    }
    __syncthreads();

    const int w    = t >> 6;
    const int lane = t & 63;
    const int mrow = lane & 15;
    const int kgrp = lane >> 4;
    const int swz  = (mrow & 7) << 3;
    const int arow = w * 16 + mrow;
    const int n    = n0 + arow;

    const bf16x8 a0 = *(const bf16x8*)&XA[((arow * 64) + 0 * 32 + kgrp * 8) ^ swz];
    const bf16x8 a1 = *(const bf16x8*)&XA[((arow * 64) + 1 * 32 + kgrp * 8) ^ swz];

    for (int sl = 0; sl < scount; ++sl) {
        const int s = sbeg + sl;
        const ushort* wt = &WT[sl * 4096];
        f32x4 acc[4];
        #pragma unroll
        for (int ct = 0; ct < 4; ++ct) {
            acc[ct] = (f32x4){0.f, 0.f, 0.f, 0.f};
            const int brow = ct * 16 + mrow;
            const bf16x8 b0 = *(const bf16x8*)&wt[((brow * 64) + 0 * 32 + kgrp * 8) ^ swz];
            const bf16x8 b1 = *(const bf16x8*)&wt[((brow * 64) + 1 * 32 + kgrp * 8) ^ swz];
            acc[ct] = __builtin_amdgcn_mfma_f32_16x16x32_bf16(b0, a0, acc[ct], 0, 0, 0);
            acc[ct] = __builtin_amdgcn_mfma_f32_16x16x32_bf16(b1, a1, acc[ct], 0, 0, 0);
        }
        if (n < NN) {
            if (s < 8) {
                #pragma unroll
                for (int ct = 0; ct < 4; ++ct) {
                    int p = __builtin_amdgcn_cvt_pk_fp8_f32(acc[ct][0], acc[ct][1], 0, false);
                    p     = __builtin_amdgcn_cvt_pk_fp8_f32(acc[ct][2], acc[ct][3], p, true);
                    *(uint32_t*)&H8[(size_t)n * 512 + s * 64 + ct * 16 + kgrp * 4] = (uint32_t)p;
                }
            } else {
                #pragma unroll
                for (int ct = 0; ct < 4; ++ct) {
                    *(float4*)&Hroot[(size_t)n * 64 + ct * 16 + kgrp * 4] =
                        make_float4(acc[ct][0], acc[ct][1], acc[ct][2], acc[ct][3]);
                }
            }
        }
    }
}

// ---------------------------------------------------------------------------
// K2: scatter edges (no atomics): p = offs[dst] + ppre[dst>>11] + rank[e].
// record = {src, q3}, q3 = 3x10-bit quantized fracs.
// ---------------------------------------------------------------------------
__global__ __launch_bounds__(256) void scatter_k(const int* __restrict__ ei,
                                                 const float* __restrict__ attr,
                                                 const int* __restrict__ offs,
                                                 const int* __restrict__ part,
                                                 const int* __restrict__ rank,
                                                 int2* __restrict__ recs) {
    __shared__ int pp[25];
    const int t = threadIdx.x;
    if (t < 25) pp[t] = part[t];
    __syncthreads();
    if (t == 0) {
        int s = 0;
        #pragma unroll
        for (int i = 0; i < 25; ++i) { int v = pp[i]; pp[i] = s; s += v; }
    }
    __syncthreads();
    int e = blockIdx.x * 256 + t;
    if (e >= NE) return;
    const int src = ei[e];
    const int dst = ei[NE + e];
    const float f0 = attr[(size_t)e * 3 + 0];
    const float f1 = attr[(size_t)e * 3 + 1];
    const float f2 = attr[(size_t)e * 3 + 2];
    const uint32_t q = (uint32_t)rintf(f0 * 1023.f)
                     | ((uint32_t)rintf(f1 * 1023.f) << 10)
                     | ((uint32_t)rintf(f2 * 1023.f) << 20);
    const int p = offs[dst] + pp[dst >> 11] + rank[e];
    recs[p] = make_int2(src, (int)q);
}

// ---------------------------------------------------------------------------
// K3: gather-aggregate (fp8 H) + fused BN partials. One node per wave.
// lane l: s=l>>3, co=(l&7)*8..+8 -> one dwordx2 (8 fp8) per edge per lane.
// ---------------------------------------------------------------------------
__global__ __launch_bounds__(256) void aggregate_k(const int* __restrict__ offs,
                                                   const int* __restrict__ part,
                                                   const int* __restrict__ deg,
                                                   const int2* __restrict__ recs,
                                                   const uint8_t* __restrict__ H8,
                                                   const float* __restrict__ Hroot,
                                                   float* __restrict__ outb,
                                                   float* __restrict__ bnps,
                                                   float* __restrict__ bnpq) {
    __shared__ int pp[25];
    __shared__ float red_s[4][64], red_q[4][64];
    const int t = threadIdx.x, lane = t & 63, w = t >> 6;
    if (t < 25) pp[t] = part[t];
    __syncthreads();
    if (t == 0) {
        int s = 0;
        #pragma unroll
        for (int i = 0; i < 25; ++i) { int v = pp[i]; pp[i] = s; s += v; }
    }
    __syncthreads();

    const int n = blockIdx.x * 4 + w;            // NN = 4*12500, no tail
    const int sidx = lane >> 3;
    const int cog  = lane & 7;
    const float sg0 = (sidx & 1) ? 1.f : -1.f, cc0 = (sidx & 1) ? 0.f : 1.f;
    const float sg1 = (sidx & 2) ? 1.f : -1.f, cc1 = (sidx & 2) ? 0.f : 1.f;
    const float sg2 = (sidx & 4) ? 1.f : -1.f, cc2 = (sidx & 4) ? 0.f : 1.f;
    const int cnt = deg[n];
    const int beg = offs[n] + pp[n >> 11];
    const int2* rp = recs + beg;
    const size_t loff = (size_t)(lane << 3);     // byte offset: s*64 + cog*8

    f32x2 acc2[4] = {(f32x2){0.f, 0.f}, (f32x2){0.f, 0.f},
                     (f32x2){0.f, 0.f}, (f32x2){0.f, 0.f}};

#define DECODE_W(qv, wv)                                                     \
    {                                                                        \
        const uint32_t q_ = (uint32_t)(qv);                                  \
        const float f0_ = (float)(q_ & 1023u) * (1.f / 1023.f);              \
        const float f1_ = (float)((q_ >> 10) & 1023u) * (1.f / 1023.f);      \
        const float f2_ = (float)((q_ >> 20) & 1023u) * (1.f / 1023.f);      \
        wv = (cc0 + sg0 * f0_) * ((cc1 + sg1 * f1_) * (cc2 + sg2 * f2_));    \
    }
#define ACCUM(wv, h)                                                         \
    {                                                                        \
        const f32x2 w2_ = {wv, wv};                                          \
        acc2[0] += w2_ * (f32x2)__builtin_amdgcn_cvt_pk_f32_fp8((int)(h).x, false); \
        acc2[1] += w2_ * (f32x2)__builtin_amdgcn_cvt_pk_f32_fp8((int)(h).x, true);  \
        acc2[2] += w2_ * (f32x2)__builtin_amdgcn_cvt_pk_f32_fp8((int)(h).y, false); \
        acc2[3] += w2_ * (f32x2)__builtin_amdgcn_cvt_pk_f32_fp8((int)(h).y, true);  \
    }

    int j = 0;
    for (; j + 3 < cnt; j += 4) {
        const int2 r0 = rp[j];
        const int2 r1 = rp[j + 1];
        const int2 r2 = rp[j + 2];
        const int2 r3 = rp[j + 3];
        const uint2 h0 = *(const uint2*)(H8 + (size_t)r0.x * 512 + loff);
        const uint2 h1 = *(const uint2*)(H8 + (size_t)r1.x * 512 + loff);
        const uint2 h2 = *(const uint2*)(H8 + (size_t)r2.x * 512 + loff);
        const uint2 h3 = *(const uint2*)(H8 + (size_t)r3.x * 512 + loff);
        float w0, w1, w2, w3;
        DECODE_W(r0.y, w0); DECODE_W(r1.y, w1);
        DECODE_W(r2.y, w2); DECODE_W(r3.y, w3);
        ACCUM(w0, h0); ACCUM(w1, h1); ACCUM(w2, h2); ACCUM(w3, h3);
    }
    for (; j < cnt; ++j) {
        const int2 r0 = rp[j];
        const uint2 h0 = *(const uint2*)(H8 + (size_t)r0.x * 512 + loff);
        float w0;
        DECODE_W(r0.y, w0);
        ACCUM(w0, h0);
    }
#undef DECODE_W
#undef ACCUM

    float accf[8] = {acc2[0].x, acc2[0].y, acc2[1].x, acc2[1].y,
                     acc2[2].x, acc2[2].y, acc2[3].x, acc2[3].y};
    #pragma unroll
    for (int k = 0; k < 8; ++k) {
        float v = accf[k];
        v += __shfl_xor(v, 8, 64);
        v += __shfl_xor(v, 16, 64);
        v += __shfl_xor(v, 32, 64);
        accf[k] = v;
    }
    if (sidx == 0) {
        const float inv = 1.f / fmaxf((float)cnt, 1.f);
        const size_t base = (size_t)n * 64 + cog * 8;
        const float4 r0 = *(const float4*)&Hroot[base];
        const float4 r1 = *(const float4*)&Hroot[base + 4];
        float vv[8];
        vv[0] = accf[0] * inv + r0.x; vv[1] = accf[1] * inv + r0.y;
        vv[2] = accf[2] * inv + r0.z; vv[3] = accf[3] * inv + r0.w;
        vv[4] = accf[4] * inv + r1.x; vv[5] = accf[5] * inv + r1.y;
        vv[6] = accf[6] * inv + r1.z; vv[7] = accf[7] * inv + r1.w;
        *(float4*)&outb[base]     = make_float4(vv[0], vv[1], vv[2], vv[3]);
        *(float4*)&outb[base + 4] = make_float4(vv[4], vv[5], vv[6], vv[7]);
        #pragma unroll
        for (int k = 0; k < 8; ++k) {
            red_s[w][cog * 8 + k] = vv[k];
            red_q[w][cog * 8 + k] = vv[k] * vv[k];
        }
    }
    __syncthreads();
    if (t < 64) {
        const float s = red_s[0][t] + red_s[1][t] + red_s[2][t] + red_s[3][t];
        const float q = red_q[0][t] + red_q[1][t] + red_q[2][t] + red_q[3][t];
        const int slot = (blockIdx.x & 63) * 64 + t;
        atomicAdd(&bnps[slot], s);
        atomicAdd(&bnpq[slot], q);
    }
}

// ---------------------------------------------------------------------------
// K4: BN + ELU. Stats preamble reduces the 64-slot partials per block.
// ---------------------------------------------------------------------------
__global__ __launch_bounds__(256) void finalize_kernel(float* __restrict__ outb,
                                                       const float* __restrict__ bnps,
                                                       const float* __restrict__ bnpq,
                                                       const float* __restrict__ gamma,
                                                       const float* __restrict__ beta) {
    __shared__ float sc_sh[64], sh_sh[64];
    const int t = threadIdx.x;
    if (t < 64) {
        float s = 0.f, q = 0.f;
        for (int k = 0; k < 64; ++k) { s += bnps[k * 64 + t]; q += bnpq[k * 64 + t]; }
        const float mean = s * (1.f / NN);
        const float var  = q * (1.f / NN) - mean * mean;
        const float sc = rsqrtf(var + EPS) * gamma[t];
        sc_sh[t] = sc;
        sh_sh[t] = beta[t] - mean * sc;
    }
    __syncthreads();
    const int total4 = NN * 16;
    for (int idx = blockIdx.x * 256 + t; idx < total4; idx += gridDim.x * 256) {
        float4 v = ((const float4*)outb)[idx];
        const int co0 = (idx & 15) * 4;
        float o[4] = {v.x, v.y, v.z, v.w};
        #pragma unroll
        for (int j = 0; j < 4; ++j) {
            const float y = o[j] * sc_sh[co0 + j] + sh_sh[co0 + j];
            o[j] = (y > 0.f) ? y : expm1f(y);
        }
        ((float4*)outb)[idx] = make_float4(o[0], o[1], o[2], o[3]);
    }
}

// ---------------------------------------------------------------------------
extern "C" void kernel_launch(void* const* d_in, const int* in_sizes, int n_in,
                              void* d_out, int out_size, void* d_ws, size_t ws_size,
                              hipStream_t stream) {
    const float* x     = (const float*)d_in[0];
    const float* attr  = (const float*)d_in[1];
    const float* W     = (const float*)d_in[2];
    const float* root  = (const float*)d_in[3];
    const float* gamma = (const float*)d_in[4];
    const float* beta  = (const float*)d_in[5];
    const int*   ei    = (const int*)d_in[6];
    float* outb = (float*)d_out;

    char* ws = (char*)d_ws;
    uint8_t* H8    = (uint8_t*)(ws);
    float*   Hroot = (float*)(ws + 25600000);
    int2*    recs  = (int2*)(ws + 38400000);
    int*     rank  = (int*)(ws + 44800000);
    int*     offs  = (int*)(ws + 48000000);
    int*     deg   = (int*)(ws + 48200000);
    int*     part  = (int*)(ws + 48400000);
    float*   bnps  = (float*)(ws + 48400128);
    float*   bnpq  = (float*)(ws + 48416512);
    ushort*  WTg   = (ushort*)(ws + 48432896);

    // zero deg + part + bn partials (contiguous tail region)
    hipMemsetAsync(ws + 48200000, 0, 232896, stream);

    prep_count_k<<<NB_WT + NB_CNT, 256, 0, stream>>>(W, root, WTg, ei, deg, rank);
    mfma_scan_k<<<NB_MFMA + NB_SCAN, 256, 0, stream>>>(x, WTg, H8, Hroot, deg, offs, part);
    scatter_k<<<NB_CNT, 256, 0, stream>>>(ei, attr, offs, part, rank, recs);
    aggregate_k<<<NN / 4, 256, 0, stream>>>(offs, part, deg, recs, H8, Hroot, outb, bnps, bnpq);
    finalize_kernel<<<256, 256, 0, stream>>>(outb, bnps, bnpq, gamma, beta);
}